// Round 1
// baseline (2380.381 us; speedup 1.0000x reference)
//
#include <hip/hip_runtime.h>

// ---------------------------------------------------------------------------
// GIN forward: 3x (segment_sum -> Linear -> BN(train) -> ReLU) + encoder chain
// N=100000 nodes, E=800000 edges, dims 86 -> 128 -> 256 -> 512, all fp32.
// ---------------------------------------------------------------------------

__global__ void count_deg_kernel(const int* __restrict__ dst, int E, int* __restrict__ deg) {
    int e = blockIdx.x * blockDim.x + threadIdx.x;
    if (e < E) atomicAdd(&deg[dst[e]], 1);
}

__global__ void scan_kernel(const int* __restrict__ deg, int M,
                            int* __restrict__ off, int* __restrict__ cur) {
    __shared__ int lds[1024];
    int t = threadIdx.x;
    int chunk = (M + 1023) >> 10;
    int b = t * chunk;
    int e = min(b + chunk, M);
    int s = 0;
    for (int i = b; i < e; ++i) s += deg[i];
    lds[t] = s;
    __syncthreads();
    for (int d = 1; d < 1024; d <<= 1) {
        int v = (t >= d) ? lds[t - d] : 0;
        __syncthreads();
        lds[t] += v;
        __syncthreads();
    }
    int run = lds[t] - s;   // exclusive prefix for this thread's chunk
    for (int i = b; i < e; ++i) { off[i] = run; cur[i] = run; run += deg[i]; }
    if (t == 1023) off[M] = lds[1023];
}

__global__ void fill_kernel(const int* __restrict__ src, const int* __restrict__ dst, int E,
                            int* __restrict__ cur, int* __restrict__ srcs) {
    int e = blockIdx.x * blockDim.x + threadIdx.x;
    if (e < E) {
        int p = atomicAdd(&cur[dst[e]], 1);
        srcs[p] = src[e];
    }
}

// One wave per destination node; lanes cover the feature dim.
template <int D>
__global__ void gather_kernel(const float* __restrict__ x, const int* __restrict__ off,
                              const int* __restrict__ srcs, float* __restrict__ agg, int M) {
    constexpr int C = (D + 63) / 64;
    int lane = threadIdx.x & 63;
    int node = blockIdx.x * 4 + (threadIdx.x >> 6);
    if (node >= M) return;
    float acc[C];
#pragma unroll
    for (int c = 0; c < C; ++c) acc[c] = 0.f;
    int j0 = off[node], j1 = off[node + 1];
    for (int j = j0; j < j1; ++j) {
        const float* row = x + (long long)srcs[j] * D;
#pragma unroll
        for (int c = 0; c < C; ++c) {
            int d = lane + 64 * c;
            if ((D % 64 == 0) || d < D) acc[c] += row[d];
        }
    }
    float* o = agg + (long long)node * D;
#pragma unroll
    for (int c = 0; c < C; ++c) {
        int d = lane + 64 * c;
        if ((D % 64 == 0) || d < D) o[d] = acc[c];
    }
}

// Per-column sum and sum-of-squares (for BN batch stats).
__global__ void colstats_kernel(const float* __restrict__ Yv, int M, int N, int rpb,
                                float* __restrict__ s1, float* __restrict__ s2) {
    int c = blockIdx.x * 128 + threadIdx.x;   // grid.x = N/128 -> always c < N
    int m0 = blockIdx.y * rpb;
    int m1 = min(m0 + rpb, M);
    float a = 0.f, b = 0.f;
    for (int m = m0; m < m1; ++m) {
        float vv = Yv[(long long)m * N + c];
        a += vv;
        b = __builtin_fmaf(vv, vv, b);
    }
    atomicAdd(&s1[c], a);
    atomicAdd(&s2[c], b);
}

__global__ void finalize_kernel(const float* __restrict__ s1, const float* __restrict__ s2,
                                const float* __restrict__ g, const float* __restrict__ bt,
                                int M, int N, float* __restrict__ scale, float* __restrict__ shift) {
    int c = blockIdx.x * 128 + threadIdx.x;
    if (c >= N) return;
    float inv = 1.0f / (float)M;
    float mean = s1[c] * inv;
    float var = s2[c] * inv - mean * mean;
    float sc = g[c] * rsqrtf(var + 1e-5f);
    scale[c] = sc;
    shift[c] = __builtin_fmaf(-mean, sc, bt[c]);
}

// ---------------------------------------------------------------------------
// Tiled fp32 GEMM, BM=BN=128, BK=16, 256 threads, 8x8 microtile.
// MODE 0: A' = (1+eps)*A + AGG (fused on load); out = A' @ B + bias        (y)
// MODE 1: out2 = relu(A@B + bias) (encoder hidden);
//         out  = out2 + relu(Y*scale + shift)                              (xv)
// MODE 2: like MODE 1 but only `out` is written (final output)
// ---------------------------------------------------------------------------
template <int K, int N, int MODE>
__global__ __launch_bounds__(256)
void gemm_kernel(const float* __restrict__ A, const float* __restrict__ AGG,
                 const float* __restrict__ EPSP,
                 const float* __restrict__ B, const float* __restrict__ bias,
                 const float* __restrict__ Y, const float* __restrict__ scale,
                 const float* __restrict__ shift,
                 float* __restrict__ out, float* __restrict__ out2, int M) {
    constexpr int BM = 128, BN = 128, BK = 16;
    __shared__ float As[BK][BM + 4];   // [k][m], padded
    __shared__ float Bs[BK][BN + 4];   // [k][n], padded
    const int t = threadIdx.x;
    const int tx = t & 15, ty = t >> 4;
    const int bm = blockIdx.y * BM;
    const int bn = blockIdx.x * BN;

    float acc[8][8];
#pragma unroll
    for (int i = 0; i < 8; ++i)
#pragma unroll
        for (int j = 0; j < 8; ++j) acc[i][j] = 0.f;

    float epsv = 0.f;
    if constexpr (MODE == 0) epsv = 1.0f + EPSP[0];

    constexpr int NK = (K + BK - 1) / BK;
    for (int kt = 0; kt < NK; ++kt) {
        const int k0 = kt * BK;
        // ---- load A tile (transposed into LDS) ----
        if constexpr (K % 4 == 0) {
#pragma unroll
            for (int q0 = 0; q0 < 2; ++q0) {
                int q = t + q0 * 256;
                int row = q >> 2, kc = (q & 3) * 4;
                int gr = bm + row, gk = k0 + kc;
                float4 av = make_float4(0.f, 0.f, 0.f, 0.f);
                if (gr < M && gk < K) {
                    av = *(const float4*)(A + (long long)gr * K + gk);
                    if constexpr (MODE == 0) {
                        float4 gv = *(const float4*)(AGG + (long long)gr * K + gk);
                        av.x = __builtin_fmaf(epsv, av.x, gv.x);
                        av.y = __builtin_fmaf(epsv, av.y, gv.y);
                        av.z = __builtin_fmaf(epsv, av.z, gv.z);
                        av.w = __builtin_fmaf(epsv, av.w, gv.w);
                    }
                }
                As[kc + 0][row] = av.x;
                As[kc + 1][row] = av.y;
                As[kc + 2][row] = av.z;
                As[kc + 3][row] = av.w;
            }
        } else {   // K % 2 == 0 (K=86): rows only 8B-aligned -> float2 loads
#pragma unroll
            for (int q0 = 0; q0 < 4; ++q0) {
                int q = t + q0 * 256;
                int row = q >> 3, kc = (q & 7) * 2;
                int gr = bm + row, gk = k0 + kc;
                float2 av = make_float2(0.f, 0.f);
                if (gr < M && gk + 1 < K) {
                    av = *(const float2*)(A + (long long)gr * K + gk);
                    if constexpr (MODE == 0) {
                        float2 gv = *(const float2*)(AGG + (long long)gr * K + gk);
                        av.x = __builtin_fmaf(epsv, av.x, gv.x);
                        av.y = __builtin_fmaf(epsv, av.y, gv.y);
                    }
                }
                As[kc + 0][row] = av.x;
                As[kc + 1][row] = av.y;
            }
        }
        // ---- load B tile ----
#pragma unroll
        for (int q0 = 0; q0 < 2; ++q0) {
            int q = t + q0 * 256;
            int kk = q >> 5, nc = (q & 31) * 4;
            int gk = k0 + kk;
            float4 bv = make_float4(0.f, 0.f, 0.f, 0.f);
            if (gk < K) bv = *(const float4*)(B + (long long)gk * N + bn + nc);
            *(float4*)&Bs[kk][nc] = bv;
        }
        __syncthreads();
        // ---- compute ----
#pragma unroll
        for (int kk = 0; kk < BK; ++kk) {
            float4 a0 = *(const float4*)&As[kk][ty * 8];
            float4 a1 = *(const float4*)&As[kk][ty * 8 + 4];
            float4 b0 = *(const float4*)&Bs[kk][tx * 4];
            float4 b1 = *(const float4*)&Bs[kk][64 + tx * 4];
            float ar[8] = {a0.x, a0.y, a0.z, a0.w, a1.x, a1.y, a1.z, a1.w};
            float br[8] = {b0.x, b0.y, b0.z, b0.w, b1.x, b1.y, b1.z, b1.w};
#pragma unroll
            for (int i = 0; i < 8; ++i)
#pragma unroll
                for (int j = 0; j < 8; ++j)
                    acc[i][j] = __builtin_fmaf(ar[i], br[j], acc[i][j]);
        }
        __syncthreads();
    }

    // ---- epilogue ----
    const int c0 = bn + tx * 4;
    const int c1 = bn + 64 + tx * 4;
    float4 bj0 = *(const float4*)(bias + c0);
    float4 bj1 = *(const float4*)(bias + c1);
    float4 sc0, sc1, sh0, sh1;
    if constexpr (MODE != 0) {
        sc0 = *(const float4*)(scale + c0);
        sc1 = *(const float4*)(scale + c1);
        sh0 = *(const float4*)(shift + c0);
        sh1 = *(const float4*)(shift + c1);
    }
#pragma unroll
    for (int i = 0; i < 8; ++i) {
        int r = bm + ty * 8 + i;
        if (r >= M) continue;
        long long base = (long long)r * N;
        if constexpr (MODE == 0) {
            float4 o0 = make_float4(acc[i][0] + bj0.x, acc[i][1] + bj0.y,
                                    acc[i][2] + bj0.z, acc[i][3] + bj0.w);
            float4 o1 = make_float4(acc[i][4] + bj1.x, acc[i][5] + bj1.y,
                                    acc[i][6] + bj1.z, acc[i][7] + bj1.w);
            *(float4*)(out + base + c0) = o0;
            *(float4*)(out + base + c1) = o1;
        } else {
            float4 y0 = *(const float4*)(Y + base + c0);
            float4 y1 = *(const float4*)(Y + base + c1);
            float4 enc0 = make_float4(fmaxf(acc[i][0] + bj0.x, 0.f), fmaxf(acc[i][1] + bj0.y, 0.f),
                                      fmaxf(acc[i][2] + bj0.z, 0.f), fmaxf(acc[i][3] + bj0.w, 0.f));
            float4 enc1 = make_float4(fmaxf(acc[i][4] + bj1.x, 0.f), fmaxf(acc[i][5] + bj1.y, 0.f),
                                      fmaxf(acc[i][6] + bj1.z, 0.f), fmaxf(acc[i][7] + bj1.w, 0.f));
            float4 o0 = make_float4(
                enc0.x + fmaxf(__builtin_fmaf(y0.x, sc0.x, sh0.x), 0.f),
                enc0.y + fmaxf(__builtin_fmaf(y0.y, sc0.y, sh0.y), 0.f),
                enc0.z + fmaxf(__builtin_fmaf(y0.z, sc0.z, sh0.z), 0.f),
                enc0.w + fmaxf(__builtin_fmaf(y0.w, sc0.w, sh0.w), 0.f));
            float4 o1 = make_float4(
                enc1.x + fmaxf(__builtin_fmaf(y1.x, sc1.x, sh1.x), 0.f),
                enc1.y + fmaxf(__builtin_fmaf(y1.y, sc1.y, sh1.y), 0.f),
                enc1.z + fmaxf(__builtin_fmaf(y1.z, sc1.z, sh1.z), 0.f),
                enc1.w + fmaxf(__builtin_fmaf(y1.w, sc1.w, sh1.w), 0.f));
            if constexpr (MODE == 1) {
                *(float4*)(out2 + base + c0) = enc0;
                *(float4*)(out2 + base + c1) = enc1;
            }
            *(float4*)(out + base + c0) = o0;
            *(float4*)(out + base + c1) = o1;
        }
    }
}

// ---------------------------------------------------------------------------

extern "C" void kernel_launch(void* const* d_in, const int* in_sizes, int n_in,
                              void* d_out, int out_size, void* d_ws, size_t ws_size,
                              hipStream_t stream) {
    const float* v   = (const float*)d_in[0];
    const int*   edg = (const int*)d_in[1];
    const float* We1 = (const float*)d_in[2];  const float* be1 = (const float*)d_in[3];
    const float* We2 = (const float*)d_in[4];  const float* be2 = (const float*)d_in[5];
    const float* We3 = (const float*)d_in[6];  const float* be3 = (const float*)d_in[7];
    const float* eps1 = (const float*)d_in[8];
    const float* W1 = (const float*)d_in[9];   const float* b1 = (const float*)d_in[10];
    const float* g1 = (const float*)d_in[11];  const float* bt1 = (const float*)d_in[12];
    const float* eps2 = (const float*)d_in[13];
    const float* W2 = (const float*)d_in[14];  const float* b2 = (const float*)d_in[15];
    const float* g2 = (const float*)d_in[16];  const float* bt2 = (const float*)d_in[17];
    const float* eps3 = (const float*)d_in[18];
    const float* W3 = (const float*)d_in[19];  const float* b3 = (const float*)d_in[20];
    const float* g3 = (const float*)d_in[21];  const float* bt3 = (const float*)d_in[22];

    const int M = in_sizes[0] / 86;
    const int E = in_sizes[1] / 2;
    const int* src = edg;
    const int* dst = edg + E;

    char* w = (char*)d_ws;
    auto carve = [&](size_t bytes) -> void* {
        void* p = (void*)w;
        w += (bytes + 255) & ~(size_t)255;
        return p;
    };
    int*   deg  = (int*)carve((size_t)M * 4);
    int*   off  = (int*)carve((size_t)(M + 1) * 4);
    int*   cur  = (int*)carve((size_t)M * 4);
    int*   srcs = (int*)carve((size_t)E * 4);
    float* agg  = (float*)carve((size_t)M * 256 * 4);
    float* yb   = (float*)carve((size_t)M * 512 * 4);
    float* v1   = (float*)carve((size_t)M * 128 * 4);
    float* v2   = (float*)carve((size_t)M * 256 * 4);
    float* xv1  = (float*)carve((size_t)M * 128 * 4);
    float* xv2  = (float*)carve((size_t)M * 256 * 4);
    float* stats = (float*)carve(3 * 2048 * 4);  // [stage]{sum, sumsq, scale, shift}[512]

    hipMemsetAsync(deg, 0, (size_t)M * 4, stream);
    hipMemsetAsync(stats, 0, 3 * 2048 * 4, stream);

    // CSR build (shared across all 3 stages)
    count_deg_kernel<<<(E + 255) / 256, 256, 0, stream>>>(dst, E, deg);
    scan_kernel<<<1, 1024, 0, stream>>>(deg, M, off, cur);
    fill_kernel<<<(E + 255) / 256, 256, 0, stream>>>(src, dst, E, cur, srcs);

    const int MB = (M + 127) / 128;
    const int RPB = 500;
    const int MR = (M + RPB - 1) / RPB;

    float* st;

    // ---------------- stage 1 (86 -> 128) ----------------
    st = stats + 0 * 2048;
    gather_kernel<86><<<(M + 3) / 4, 256, 0, stream>>>(v, off, srcs, agg, M);
    gemm_kernel<86, 128, 0><<<dim3(1, MB), 256, 0, stream>>>(
        v, agg, eps1, W1, b1, nullptr, nullptr, nullptr, yb, nullptr, M);
    colstats_kernel<<<dim3(1, MR), 128, 0, stream>>>(yb, M, 128, RPB, st, st + 512);
    finalize_kernel<<<1, 128, 0, stream>>>(st, st + 512, g1, bt1, M, 128, st + 1024, st + 1536);
    gemm_kernel<86, 128, 1><<<dim3(1, MB), 256, 0, stream>>>(
        v, nullptr, nullptr, We1, be1, yb, st + 1024, st + 1536, xv1, v1, M);

    // ---------------- stage 2 (128 -> 256) ----------------
    st = stats + 1 * 2048;
    gather_kernel<128><<<(M + 3) / 4, 256, 0, stream>>>(xv1, off, srcs, agg, M);
    gemm_kernel<128, 256, 0><<<dim3(2, MB), 256, 0, stream>>>(
        xv1, agg, eps2, W2, b2, nullptr, nullptr, nullptr, yb, nullptr, M);
    colstats_kernel<<<dim3(2, MR), 128, 0, stream>>>(yb, M, 256, RPB, st, st + 512);
    finalize_kernel<<<2, 128, 0, stream>>>(st, st + 512, g2, bt2, M, 256, st + 1024, st + 1536);
    gemm_kernel<128, 256, 1><<<dim3(2, MB), 256, 0, stream>>>(
        v1, nullptr, nullptr, We2, be2, yb, st + 1024, st + 1536, xv2, v2, M);

    // ---------------- stage 3 (256 -> 512) ----------------
    st = stats + 2 * 2048;
    gather_kernel<256><<<(M + 3) / 4, 256, 0, stream>>>(xv2, off, srcs, agg, M);
    gemm_kernel<256, 512, 0><<<dim3(4, MB), 256, 0, stream>>>(
        xv2, agg, eps3, W3, b3, nullptr, nullptr, nullptr, yb, nullptr, M);
    colstats_kernel<<<dim3(4, MR), 128, 0, stream>>>(yb, M, 512, RPB, st, st + 512);
    finalize_kernel<<<4, 128, 0, stream>>>(st, st + 512, g3, bt3, M, 512, st + 1024, st + 1536);
    gemm_kernel<256, 512, 2><<<dim3(4, MB), 256, 0, stream>>>(
        v2, nullptr, nullptr, We3, be3, yb, st + 1024, st + 1536, (float*)d_out, nullptr, M);
}

// Round 3
// 1183.352 us; speedup vs baseline: 2.0116x; 2.0116x over previous
//
#include <hip/hip_runtime.h>

// ---------------------------------------------------------------------------
// GIN forward, bf16-MFMA version (resubmit of round-1 after infra failure).
// Pipeline per stage: gather_h (CSR segsum + (1+eps)x, bf16) ->
//   MFMA GEMM MODE0 (y = h@W + b, fp32 out, fused BN col-stats) ->
//   finalize (scale/shift) ->
//   MFMA GEMM MODE1/2 (enc = relu(v_{k-1}@We+be); out = enc + relu(y*sc+sh)).
// Stage-1 K=86 zero-padded to 128. All activations bf16; yb + BN stats fp32.
// ---------------------------------------------------------------------------

typedef short short8 __attribute__((ext_vector_type(8)));
typedef float f32x4 __attribute__((ext_vector_type(4)));

__device__ __forceinline__ unsigned short f2bf(float f) {
    unsigned int u = __float_as_uint(f);
    u = (u + 0x7fffu + ((u >> 16) & 1u)) >> 16;
    return (unsigned short)u;
}
__device__ __forceinline__ float bflo(unsigned int u) { return __uint_as_float(u << 16); }
__device__ __forceinline__ float bfhi(unsigned int u) { return __uint_as_float(u & 0xffff0000u); }
__device__ __forceinline__ unsigned int packbf2(float lo, float hi) {
    return (unsigned int)f2bf(lo) | ((unsigned int)f2bf(hi) << 16);
}

// async global->LDS, 16B per lane; dest = uniform base + lane*16 (HW rule)
__device__ __forceinline__ void gload16(const void* g, void* l) {
    __builtin_amdgcn_global_load_lds(
        (__attribute__((address_space(1))) const unsigned int*)g,
        (__attribute__((address_space(3))) unsigned int*)l, 16, 0, 0);
}

// ------------------------------- CSR build ---------------------------------

__global__ void count_deg_kernel(const int* __restrict__ dst, int E, int* __restrict__ deg) {
    int e = blockIdx.x * blockDim.x + threadIdx.x;
    if (e < E) atomicAdd(&deg[dst[e]], 1);
}

__global__ void scan_kernel(const int* __restrict__ deg, int M,
                            int* __restrict__ off, int* __restrict__ cur) {
    __shared__ int lds[1024];
    int t = threadIdx.x;
    int chunk = (M + 1023) >> 10;
    int b = t * chunk;
    int e = min(b + chunk, M);
    int s = 0;
    for (int i = b; i < e; ++i) s += deg[i];
    lds[t] = s;
    __syncthreads();
    for (int d = 1; d < 1024; d <<= 1) {
        int v = (t >= d) ? lds[t - d] : 0;
        __syncthreads();
        lds[t] += v;
        __syncthreads();
    }
    int run = lds[t] - s;
    for (int i = b; i < e; ++i) { off[i] = run; cur[i] = run; run += deg[i]; }
    if (t == 1023) off[M] = lds[1023];
}

__global__ void fill_kernel(const int* __restrict__ src, const int* __restrict__ dst, int E,
                            int* __restrict__ cur, int* __restrict__ srcs) {
    int e = blockIdx.x * blockDim.x + threadIdx.x;
    if (e < E) {
        int p = atomicAdd(&cur[dst[e]], 1);
        srcs[p] = src[e];
    }
}

// ------------------------- gather: h = (1+eps)x + segsum ---------------------
// bf16 in / bf16 out, D = padded feature dim (multiple of 128).
template <int D>
__global__ __launch_bounds__(256)
void gather_h_kernel(const unsigned short* __restrict__ x, const int* __restrict__ off,
                     const int* __restrict__ srcs, const float* __restrict__ epsp,
                     unsigned short* __restrict__ h, int M) {
    constexpr int C = D / 128;   // uint (2xbf16) chunks per lane
    int lane = threadIdx.x & 63;
    int node = blockIdx.x * 4 + (threadIdx.x >> 6);
    if (node >= M) return;
    float accx[C], accy[C];
#pragma unroll
    for (int c = 0; c < C; ++c) { accx[c] = 0.f; accy[c] = 0.f; }
    int j0 = off[node], j1 = off[node + 1];
    for (int j = j0; j < j1; ++j) {
        const unsigned int* row = (const unsigned int*)(x + (size_t)srcs[j] * D);
#pragma unroll
        for (int c = 0; c < C; ++c) {
            unsigned int u = row[lane + c * 64];
            accx[c] += bflo(u);
            accy[c] += bfhi(u);
        }
    }
    float e = 1.0f + epsp[0];
    const unsigned int* self = (const unsigned int*)(x + (size_t)node * D);
    unsigned int* out = (unsigned int*)(h + (size_t)node * D);
#pragma unroll
    for (int c = 0; c < C; ++c) {
        unsigned int u = self[lane + c * 64];
        float lo = __builtin_fmaf(e, bflo(u), accx[c]);
        float hi = __builtin_fmaf(e, bfhi(u), accy[c]);
        out[lane + c * 64] = packbf2(lo, hi);
    }
}

// ------------------------------ prep kernels --------------------------------

// W [K][N] fp32 -> WT [N][Kp] bf16 (zero pad k >= K)
__global__ void prep_wt_kernel(const float* __restrict__ W, unsigned short* __restrict__ WT,
                               int K, int N, int Kp) {
    int id = blockIdx.x * 256 + threadIdx.x;
    if (id >= N * Kp) return;
    int n = id / Kp, k = id - n * Kp;
    float v = (k < K) ? W[(size_t)k * N + n] : 0.f;
    WT[id] = f2bf(v);
}

// v [M][86] fp32 -> vbf [M][128] bf16 zero-padded
__global__ void conv_v_kernel(const float* __restrict__ v, unsigned short* __restrict__ vbf, int M) {
    int id = blockIdx.x * 256 + threadIdx.x;
    if (id >= M * 128) return;
    int r = id >> 7, k = id & 127;
    float x = (k < 86) ? v[(size_t)r * 86 + k] : 0.f;
    vbf[id] = f2bf(x);
}

__global__ void finalize_kernel(const float* __restrict__ s1, const float* __restrict__ s2,
                                const float* __restrict__ g, const float* __restrict__ bt,
                                int M, int N, float* __restrict__ scale, float* __restrict__ shift) {
    int c = blockIdx.x * 128 + threadIdx.x;
    if (c >= N) return;
    float inv = 1.0f / (float)M;
    float mean = s1[c] * inv;
    float var = s2[c] * inv - mean * mean;
    float sc = g[c] * rsqrtf(var + 1e-5f);
    scale[c] = sc;
    shift[c] = __builtin_fmaf(-mean, sc, bt[c]);
}

// ------------------------------ MFMA GEMM -----------------------------------
// BM=BN=128, BK=64, 256 threads (4 waves, 2x2 of 64x64), 16x16x32 bf16 MFMA.
// A [M][Kp] bf16 row-major; WT = B^T [N][Kp] bf16. LDS tiles [128][64] with
// chunk-XOR swizzle (chunk ^= row&7, 16B chunks), staged via global_load_lds
// with pre-swizzled global source (linear LDS dest).
// MODE 0: out0(f32) = A@B + bias; fused per-column sum/sumsq atomics.
// MODE 1: enc = relu(A@B+bias) -> out_v (bf16); out0(bf16) = enc + relu(Y*sc+sh)
// MODE 2: out0(f32)  = relu(A@B+bias) + relu(Y*sc+sh)
template <int Kp, int N, int MODE>
__global__ __launch_bounds__(256, 2)
void mfma_gemm(const unsigned short* __restrict__ A, const unsigned short* __restrict__ WT,
               const float* __restrict__ bias,
               const float* __restrict__ Y, const float* __restrict__ scale,
               const float* __restrict__ shift,
               float* __restrict__ s1g, float* __restrict__ s2g,
               void* __restrict__ out0, unsigned short* __restrict__ out_v, int M) {
    constexpr int BK = 64;
    __shared__ unsigned short lA[128 * BK];
    __shared__ unsigned short lB[128 * BK];
    const int t = threadIdx.x;
    const int l = t & 63, w = t >> 6;
    const int wr = w >> 1, wc = w & 1;
    const int bm = blockIdx.y * 128, bn = blockIdx.x * 128;
    const int ln = l & 15, lg = l >> 4;

    f32x4 acc[4][4] = {};

    const int srow0 = w * 32;           // this wave stages rows [srow0, srow0+32)
    const int srow = srow0 + (l >> 3);  // + i*8 per instruction
    const int sc8 = l & 7;              // 16B chunk slot this lane fills

    for (int k0 = 0; k0 < Kp; k0 += BK) {
#pragma unroll
        for (int i = 0; i < 4; ++i) {
            int row = srow + i * 8;
            int gc = sc8 ^ (row & 7);   // pre-swizzled global chunk
            int gra = bm + row;
            gra = gra < M ? gra : M - 1;
            gload16(A + (size_t)gra * Kp + k0 + gc * 8, &lA[(srow0 + i * 8) * BK]);
            gload16(WT + (size_t)(bn + row) * Kp + k0 + gc * 8, &lB[(srow0 + i * 8) * BK]);
        }
        __syncthreads();
#pragma unroll
        for (int ks = 0; ks < 2; ++ks) {
            short8 af[4], bfr[4];
#pragma unroll
            for (int m = 0; m < 4; ++m) {
                int row = wr * 64 + m * 16 + ln;
                int g = ks * 4 + lg;
                af[m] = *(const short8*)&lA[row * BK + ((g ^ (row & 7)) * 8)];
            }
#pragma unroll
            for (int n = 0; n < 4; ++n) {
                int row = wc * 64 + n * 16 + ln;
                int g = ks * 4 + lg;
                bfr[n] = *(const short8*)&lB[row * BK + ((g ^ (row & 7)) * 8)];
            }
#pragma unroll
            for (int m = 0; m < 4; ++m)
#pragma unroll
                for (int n = 0; n < 4; ++n)
                    acc[m][n] = __builtin_amdgcn_mfma_f32_16x16x32_bf16(af[m], bfr[n], acc[m][n], 0, 0, 0);
        }
        __syncthreads();
    }

    // ---- epilogue ----
    const int col0 = bn + wc * 64 + ln;   // + n*16
    float bj[4];
#pragma unroll
    for (int n = 0; n < 4; ++n) bj[n] = bias[col0 + n * 16];

    if constexpr (MODE == 0) {
        float* outp = (float*)out0;
        float s1l[4] = {0.f, 0.f, 0.f, 0.f}, s2l[4] = {0.f, 0.f, 0.f, 0.f};
#pragma unroll
        for (int m = 0; m < 4; ++m) {
#pragma unroll
            for (int r = 0; r < 4; ++r) {
                int row = bm + wr * 64 + m * 16 + lg * 4 + r;
                if (row < M) {
                    size_t base = (size_t)row * N;
#pragma unroll
                    for (int n = 0; n < 4; ++n) {
                        float y = acc[m][n][r] + bj[n];
                        outp[base + col0 + n * 16] = y;
                        s1l[n] += y;
                        s2l[n] = __builtin_fmaf(y, y, s2l[n]);
                    }
                }
            }
        }
#pragma unroll
        for (int n = 0; n < 4; ++n) {
            s1l[n] += __shfl_xor(s1l[n], 16);
            s1l[n] += __shfl_xor(s1l[n], 32);
            s2l[n] += __shfl_xor(s2l[n], 16);
            s2l[n] += __shfl_xor(s2l[n], 32);
        }
        __syncthreads();
        float* red = (float*)lA;   // 512 floats used
        if (lg == 0) {
#pragma unroll
            for (int n = 0; n < 4; ++n) {
                int cidx = wc * 64 + n * 16 + ln;
                red[wr * 256 + cidx] = s1l[n];
                red[wr * 256 + 128 + cidx] = s2l[n];
            }
        }
        __syncthreads();
        if (t < 128) {
            atomicAdd(&s1g[bn + t], red[t] + red[256 + t]);
            atomicAdd(&s2g[bn + t], red[128 + t] + red[384 + t]);
        }
    } else {
        float scl[4], shf[4];
#pragma unroll
        for (int n = 0; n < 4; ++n) {
            scl[n] = scale[col0 + n * 16];
            shf[n] = shift[col0 + n * 16];
        }
#pragma unroll
        for (int m = 0; m < 4; ++m) {
#pragma unroll
            for (int r = 0; r < 4; ++r) {
                int row = bm + wr * 64 + m * 16 + lg * 4 + r;
                if (row >= M) continue;
                size_t base = (size_t)row * N;
#pragma unroll
                for (int n = 0; n < 4; ++n) {
                    size_t idx = base + col0 + n * 16;
                    float enc = fmaxf(acc[m][n][r] + bj[n], 0.f);
                    float yv = Y[idx];
                    float o = enc + fmaxf(__builtin_fmaf(yv, scl[n], shf[n]), 0.f);
                    if constexpr (MODE == 1) {
                        out_v[idx] = f2bf(enc);
                        ((unsigned short*)out0)[idx] = f2bf(o);
                    } else {
                        ((float*)out0)[idx] = o;
                    }
                }
            }
        }
    }
}

// ---------------------------------------------------------------------------

extern "C" void kernel_launch(void* const* d_in, const int* in_sizes, int n_in,
                              void* d_out, int out_size, void* d_ws, size_t ws_size,
                              hipStream_t stream) {
    const float* v   = (const float*)d_in[0];
    const int*   edg = (const int*)d_in[1];
    const float* We1 = (const float*)d_in[2];  const float* be1 = (const float*)d_in[3];
    const float* We2 = (const float*)d_in[4];  const float* be2 = (const float*)d_in[5];
    const float* We3 = (const float*)d_in[6];  const float* be3 = (const float*)d_in[7];
    const float* eps1 = (const float*)d_in[8];
    const float* W1 = (const float*)d_in[9];   const float* b1 = (const float*)d_in[10];
    const float* g1 = (const float*)d_in[11];  const float* bt1 = (const float*)d_in[12];
    const float* eps2 = (const float*)d_in[13];
    const float* W2 = (const float*)d_in[14];  const float* b2 = (const float*)d_in[15];
    const float* g2 = (const float*)d_in[16];  const float* bt2 = (const float*)d_in[17];
    const float* eps3 = (const float*)d_in[18];
    const float* W3 = (const float*)d_in[19];  const float* b3 = (const float*)d_in[20];
    const float* g3 = (const float*)d_in[21];  const float* bt3 = (const float*)d_in[22];

    const int M = in_sizes[0] / 86;
    const int E = in_sizes[1] / 2;
    const int* src = edg;
    const int* dst = edg + E;

    char* w = (char*)d_ws;
    auto carve = [&](size_t bytes) -> void* {
        void* p = (void*)w;
        w += (bytes + 255) & ~(size_t)255;
        return p;
    };
    int*   deg  = (int*)carve((size_t)M * 4);
    int*   off  = (int*)carve((size_t)(M + 1) * 4);
    int*   cur  = (int*)carve((size_t)M * 4);
    int*   srcs = (int*)carve((size_t)E * 4);
    unsigned short* vbf = (unsigned short*)carve((size_t)M * 128 * 2);
    unsigned short* hb  = (unsigned short*)carve((size_t)M * 256 * 2);
    float* yb   = (float*)carve((size_t)M * 512 * 4);
    unsigned short* v1  = (unsigned short*)carve((size_t)M * 128 * 2);
    unsigned short* v2  = (unsigned short*)carve((size_t)M * 256 * 2);
    unsigned short* xv1 = (unsigned short*)carve((size_t)M * 128 * 2);
    unsigned short* xv2 = (unsigned short*)carve((size_t)M * 256 * 2);
    unsigned short* WT1g = (unsigned short*)carve(128 * 128 * 2);
    unsigned short* WT1e = (unsigned short*)carve(128 * 128 * 2);
    unsigned short* WT2g = (unsigned short*)carve(256 * 128 * 2);
    unsigned short* WT2e = (unsigned short*)carve(256 * 128 * 2);
    unsigned short* WT3g = (unsigned short*)carve(512 * 256 * 2);
    unsigned short* WT3e = (unsigned short*)carve(512 * 256 * 2);
    float* stats = (float*)carve(3 * 2048 * 4);  // per stage: s1,s2,scale,shift [512]

    hipMemsetAsync(deg, 0, (size_t)M * 4, stream);
    hipMemsetAsync(stats, 0, 3 * 2048 * 4, stream);

    // input conversion + weight prep
    conv_v_kernel<<<(M * 128 + 255) / 256, 256, 0, stream>>>(v, vbf, M);
    prep_wt_kernel<<<(128 * 128 + 255) / 256, 256, 0, stream>>>(W1, WT1g, 86, 128, 128);
    prep_wt_kernel<<<(128 * 128 + 255) / 256, 256, 0, stream>>>(We1, WT1e, 86, 128, 128);
    prep_wt_kernel<<<(256 * 128 + 255) / 256, 256, 0, stream>>>(W2, WT2g, 128, 256, 128);
    prep_wt_kernel<<<(256 * 128 + 255) / 256, 256, 0, stream>>>(We2, WT2e, 128, 256, 128);
    prep_wt_kernel<<<(512 * 256 + 255) / 256, 256, 0, stream>>>(W3, WT3g, 256, 512, 256);
    prep_wt_kernel<<<(512 * 256 + 255) / 256, 256, 0, stream>>>(We3, WT3e, 256, 512, 256);

    // CSR build
    count_deg_kernel<<<(E + 255) / 256, 256, 0, stream>>>(dst, E, deg);
    scan_kernel<<<1, 1024, 0, stream>>>(deg, M, off, cur);
    fill_kernel<<<(E + 255) / 256, 256, 0, stream>>>(src, dst, E, cur, srcs);

    const int MB = (M + 127) / 128;
    float* st;

    // ---------------- stage 1 (86(->128) -> 128) ----------------
    st = stats + 0 * 2048;
    gather_h_kernel<128><<<(M + 3) / 4, 256, 0, stream>>>(vbf, off, srcs, eps1, hb, M);
    mfma_gemm<128, 128, 0><<<dim3(1, MB), 256, 0, stream>>>(
        hb, WT1g, b1, nullptr, nullptr, nullptr, st, st + 512, yb, nullptr, M);
    finalize_kernel<<<1, 128, 0, stream>>>(st, st + 512, g1, bt1, M, 128, st + 1024, st + 1536);
    mfma_gemm<128, 128, 1><<<dim3(1, MB), 256, 0, stream>>>(
        vbf, WT1e, be1, yb, st + 1024, st + 1536, nullptr, nullptr, xv1, v1, M);

    // ---------------- stage 2 (128 -> 256) ----------------
    st = stats + 1 * 2048;
    gather_h_kernel<128><<<(M + 3) / 4, 256, 0, stream>>>(xv1, off, srcs, eps2, hb, M);
    mfma_gemm<128, 256, 0><<<dim3(2, MB), 256, 0, stream>>>(
        hb, WT2g, b2, nullptr, nullptr, nullptr, st, st + 512, yb, nullptr, M);
    finalize_kernel<<<2, 128, 0, stream>>>(st, st + 512, g2, bt2, M, 256, st + 1024, st + 1536);
    mfma_gemm<128, 256, 1><<<dim3(2, MB), 256, 0, stream>>>(
        v1, WT2e, be2, yb, st + 1024, st + 1536, nullptr, nullptr, xv2, v2, M);

    // ---------------- stage 3 (256 -> 512) ----------------
    st = stats + 2 * 2048;
    gather_h_kernel<256><<<(M + 3) / 4, 256, 0, stream>>>(xv2, off, srcs, eps3, hb, M);
    mfma_gemm<256, 512, 0><<<dim3(4, MB), 256, 0, stream>>>(
        hb, WT3g, b3, nullptr, nullptr, nullptr, st, st + 512, yb, nullptr, M);
    finalize_kernel<<<4, 128, 0, stream>>>(st, st + 512, g3, bt3, M, 512, st + 1024, st + 1536);
    mfma_gemm<256, 512, 2><<<dim3(4, MB), 256, 0, stream>>>(
        v2, WT3e, be3, yb, st + 1024, st + 1536, nullptr, nullptr, (float*)d_out, nullptr, M);
}

// Round 5
// 915.788 us; speedup vs baseline: 2.5993x; 1.2922x over previous
//
#include <hip/hip_runtime.h>

// ---------------------------------------------------------------------------
// GIN forward, bf16-MFMA version (resubmit after infra failure).
// Round-3 changes: (1) 3-kernel coalesced CSR scan (was 231us single-block),
// (2) pre-BN buffer yb stored bf16 (stats still fp32-exact in GEMM epilogue).
// ---------------------------------------------------------------------------

typedef short short8 __attribute__((ext_vector_type(8)));
typedef float f32x4 __attribute__((ext_vector_type(4)));

__device__ __forceinline__ unsigned short f2bf(float f) {
    unsigned int u = __float_as_uint(f);
    u = (u + 0x7fffu + ((u >> 16) & 1u)) >> 16;
    return (unsigned short)u;
}
__device__ __forceinline__ float bflo(unsigned int u) { return __uint_as_float(u << 16); }
__device__ __forceinline__ float bfhi(unsigned int u) { return __uint_as_float(u & 0xffff0000u); }
__device__ __forceinline__ unsigned int packbf2(float lo, float hi) {
    return (unsigned int)f2bf(lo) | ((unsigned int)f2bf(hi) << 16);
}
__device__ __forceinline__ float bf2f(unsigned short s) {
    return __uint_as_float(((unsigned int)s) << 16);
}

// async global->LDS, 16B per lane; dest = uniform base + lane*16 (HW rule)
__device__ __forceinline__ void gload16(const void* g, void* l) {
    __builtin_amdgcn_global_load_lds(
        (__attribute__((address_space(1))) const unsigned int*)g,
        (__attribute__((address_space(3))) unsigned int*)l, 16, 0, 0);
}

// ------------------------------- CSR build ---------------------------------

__global__ void count_deg_kernel(const int* __restrict__ dst, int E, int* __restrict__ deg) {
    int e = blockIdx.x * blockDim.x + threadIdx.x;
    if (e < E) atomicAdd(&deg[dst[e]], 1);
}

// A: per-block (1024 elems, 256 thr x int4) reduction -> bsum[b]
__global__ __launch_bounds__(256)
void scan_reduce_kernel(const int* __restrict__ deg, int M, int* __restrict__ bsum) {
    __shared__ int ws[4];
    int t = threadIdx.x;
    int i0 = blockIdx.x * 1024 + t * 4;
    int s = 0;
    if (i0 + 3 < M) {
        int4 v = *(const int4*)(deg + i0);
        s = v.x + v.y + v.z + v.w;
    } else {
        for (int i = i0; i < min(i0 + 4, M); ++i) s += deg[i];
    }
    for (int d = 1; d < 64; d <<= 1) s += __shfl_xor(s, d);
    if ((t & 63) == 0) ws[t >> 6] = s;
    __syncthreads();
    if (t == 0) bsum[blockIdx.x] = ws[0] + ws[1] + ws[2] + ws[3];
}

// B: single block scans bsum[NB] -> boff (exclusive), writes off[M]=total
__global__ __launch_bounds__(1024)
void scan_bsum_kernel(const int* __restrict__ bsum, int NB,
                      int* __restrict__ boff, int* __restrict__ off, int M) {
    __shared__ int lds[1024];
    int t = threadIdx.x;
    int v = (t < NB) ? bsum[t] : 0;
    lds[t] = v;
    __syncthreads();
    for (int d = 1; d < 1024; d <<= 1) {
        int x = (t >= d) ? lds[t - d] : 0;
        __syncthreads();
        lds[t] += x;
        __syncthreads();
    }
    if (t < NB) boff[t] = lds[t] - v;
    if (t == NB - 1) off[M] = lds[t];
}

// C: per-block local exclusive scan + block offset -> off[], cur[]
__global__ __launch_bounds__(256)
void scan_apply_kernel(const int* __restrict__ deg, int M, const int* __restrict__ boff,
                       int* __restrict__ off, int* __restrict__ cur) {
    __shared__ int lds[256];
    int t = threadIdx.x;
    int i0 = blockIdx.x * 1024 + t * 4;
    int d0 = 0, d1 = 0, d2 = 0, d3 = 0;
    if (i0 + 3 < M) {
        int4 v = *(const int4*)(deg + i0);
        d0 = v.x; d1 = v.y; d2 = v.z; d3 = v.w;
    } else {
        if (i0 + 0 < M) d0 = deg[i0 + 0];
        if (i0 + 1 < M) d1 = deg[i0 + 1];
        if (i0 + 2 < M) d2 = deg[i0 + 2];
        if (i0 + 3 < M) d3 = deg[i0 + 3];
    }
    int s = d0 + d1 + d2 + d3;
    lds[t] = s;
    __syncthreads();
    for (int d = 1; d < 256; d <<= 1) {
        int x = (t >= d) ? lds[t - d] : 0;
        __syncthreads();
        lds[t] += x;
        __syncthreads();
    }
    int e = lds[t] - s + boff[blockIdx.x];
    int e0 = e, e1 = e + d0, e2 = e1 + d1, e3 = e2 + d2;
    if (i0 + 3 < M) {
        *(int4*)(off + i0) = make_int4(e0, e1, e2, e3);
        *(int4*)(cur + i0) = make_int4(e0, e1, e2, e3);
    } else {
        if (i0 + 0 < M) { off[i0 + 0] = e0; cur[i0 + 0] = e0; }
        if (i0 + 1 < M) { off[i0 + 1] = e1; cur[i0 + 1] = e1; }
        if (i0 + 2 < M) { off[i0 + 2] = e2; cur[i0 + 2] = e2; }
        if (i0 + 3 < M) { off[i0 + 3] = e3; cur[i0 + 3] = e3; }
    }
}

__global__ void fill_kernel(const int* __restrict__ src, const int* __restrict__ dst, int E,
                            int* __restrict__ cur, int* __restrict__ srcs) {
    int e = blockIdx.x * blockDim.x + threadIdx.x;
    if (e < E) {
        int p = atomicAdd(&cur[dst[e]], 1);
        srcs[p] = src[e];
    }
}

// ------------------------- gather: h = (1+eps)x + segsum ---------------------
template <int D>
__global__ __launch_bounds__(256)
void gather_h_kernel(const unsigned short* __restrict__ x, const int* __restrict__ off,
                     const int* __restrict__ srcs, const float* __restrict__ epsp,
                     unsigned short* __restrict__ h, int M) {
    constexpr int C = D / 128;   // uint (2xbf16) chunks per lane
    int lane = threadIdx.x & 63;
    int node = blockIdx.x * 4 + (threadIdx.x >> 6);
    if (node >= M) return;
    float accx[C], accy[C];
#pragma unroll
    for (int c = 0; c < C; ++c) { accx[c] = 0.f; accy[c] = 0.f; }
    int j0 = off[node], j1 = off[node + 1];
    for (int j = j0; j < j1; ++j) {
        const unsigned int* row = (const unsigned int*)(x + (size_t)srcs[j] * D);
#pragma unroll
        for (int c = 0; c < C; ++c) {
            unsigned int u = row[lane + c * 64];
            accx[c] += bflo(u);
            accy[c] += bfhi(u);
        }
    }
    float e = 1.0f + epsp[0];
    const unsigned int* self = (const unsigned int*)(x + (size_t)node * D);
    unsigned int* out = (unsigned int*)(h + (size_t)node * D);
#pragma unroll
    for (int c = 0; c < C; ++c) {
        unsigned int u = self[lane + c * 64];
        float lo = __builtin_fmaf(e, bflo(u), accx[c]);
        float hi = __builtin_fmaf(e, bfhi(u), accy[c]);
        out[lane + c * 64] = packbf2(lo, hi);
    }
}

// ------------------------------ prep kernels --------------------------------

__global__ void prep_wt_kernel(const float* __restrict__ W, unsigned short* __restrict__ WT,
                               int K, int N, int Kp) {
    int id = blockIdx.x * 256 + threadIdx.x;
    if (id >= N * Kp) return;
    int n = id / Kp, k = id - n * Kp;
    float v = (k < K) ? W[(size_t)k * N + n] : 0.f;
    WT[id] = f2bf(v);
}

__global__ void conv_v_kernel(const float* __restrict__ v, unsigned short* __restrict__ vbf, int M) {
    int id = blockIdx.x * 256 + threadIdx.x;
    if (id >= M * 128) return;
    int r = id >> 7, k = id & 127;
    float x = (k < 86) ? v[(size_t)r * 86 + k] : 0.f;
    vbf[id] = f2bf(x);
}

__global__ void finalize_kernel(const float* __restrict__ s1, const float* __restrict__ s2,
                                const float* __restrict__ g, const float* __restrict__ bt,
                                int M, int N, float* __restrict__ scale, float* __restrict__ shift) {
    int c = blockIdx.x * 128 + threadIdx.x;
    if (c >= N) return;
    float inv = 1.0f / (float)M;
    float mean = s1[c] * inv;
    float var = s2[c] * inv - mean * mean;
    float sc = g[c] * rsqrtf(var + 1e-5f);
    scale[c] = sc;
    shift[c] = __builtin_fmaf(-mean, sc, bt[c]);
}

// ------------------------------ MFMA GEMM -----------------------------------
// BM=BN=128, BK=64, 256 threads (4 waves, 2x2 of 64x64), 16x16x32 bf16 MFMA.
// MODE 0: yb(bf16) = A@B + bias; fused fp32 per-column sum/sumsq atomics.
// MODE 1: enc = relu(A@B+bias) -> out_v (bf16); out0(bf16) = enc + relu(Y*sc+sh)
// MODE 2: out0(f32)  = relu(A@B+bias) + relu(Y*sc+sh)
template <int Kp, int N, int MODE>
__global__ __launch_bounds__(256, 2)
void mfma_gemm(const unsigned short* __restrict__ A, const unsigned short* __restrict__ WT,
               const float* __restrict__ bias,
               const unsigned short* __restrict__ Y, const float* __restrict__ scale,
               const float* __restrict__ shift,
               float* __restrict__ s1g, float* __restrict__ s2g,
               void* __restrict__ out0, unsigned short* __restrict__ out_v, int M) {
    constexpr int BK = 64;
    __shared__ unsigned short lA[128 * BK];
    __shared__ unsigned short lB[128 * BK];
    const int t = threadIdx.x;
    const int l = t & 63, w = t >> 6;
    const int wr = w >> 1, wc = w & 1;
    const int bm = blockIdx.y * 128, bn = blockIdx.x * 128;
    const int ln = l & 15, lg = l >> 4;

    f32x4 acc[4][4] = {};

    const int srow0 = w * 32;           // this wave stages rows [srow0, srow0+32)
    const int srow = srow0 + (l >> 3);  // + i*8 per instruction
    const int sc8 = l & 7;              // 16B chunk slot this lane fills

    for (int k0 = 0; k0 < Kp; k0 += BK) {
#pragma unroll
        for (int i = 0; i < 4; ++i) {
            int row = srow + i * 8;
            int gc = sc8 ^ (row & 7);   // pre-swizzled global chunk
            int gra = bm + row;
            gra = gra < M ? gra : M - 1;
            gload16(A + (size_t)gra * Kp + k0 + gc * 8, &lA[(srow0 + i * 8) * BK]);
            gload16(WT + (size_t)(bn + row) * Kp + k0 + gc * 8, &lB[(srow0 + i * 8) * BK]);
        }
        __syncthreads();
#pragma unroll
        for (int ks = 0; ks < 2; ++ks) {
            short8 af[4], bfr[4];
#pragma unroll
            for (int m = 0; m < 4; ++m) {
                int row = wr * 64 + m * 16 + ln;
                int g = ks * 4 + lg;
                af[m] = *(const short8*)&lA[row * BK + ((g ^ (row & 7)) * 8)];
            }
#pragma unroll
            for (int n = 0; n < 4; ++n) {
                int row = wc * 64 + n * 16 + ln;
                int g = ks * 4 + lg;
                bfr[n] = *(const short8*)&lB[row * BK + ((g ^ (row & 7)) * 8)];
            }
#pragma unroll
            for (int m = 0; m < 4; ++m)
#pragma unroll
                for (int n = 0; n < 4; ++n)
                    acc[m][n] = __builtin_amdgcn_mfma_f32_16x16x32_bf16(af[m], bfr[n], acc[m][n], 0, 0, 0);
        }
        __syncthreads();
    }

    // ---- epilogue ----
    const int col0 = bn + wc * 64 + ln;   // + n*16
    float bj[4];
#pragma unroll
    for (int n = 0; n < 4; ++n) bj[n] = bias[col0 + n * 16];

    if constexpr (MODE == 0) {
        unsigned short* outp = (unsigned short*)out0;
        float s1l[4] = {0.f, 0.f, 0.f, 0.f}, s2l[4] = {0.f, 0.f, 0.f, 0.f};
#pragma unroll
        for (int m = 0; m < 4; ++m) {
#pragma unroll
            for (int r = 0; r < 4; ++r) {
                int row = bm + wr * 64 + m * 16 + lg * 4 + r;
                if (row < M) {
                    size_t base = (size_t)row * N;
#pragma unroll
                    for (int n = 0; n < 4; ++n) {
                        float y = acc[m][n][r] + bj[n];
                        outp[base + col0 + n * 16] = f2bf(y);
                        s1l[n] += y;
                        s2l[n] = __builtin_fmaf(y, y, s2l[n]);
                    }
                }
            }
        }
#pragma unroll
        for (int n = 0; n < 4; ++n) {
            s1l[n] += __shfl_xor(s1l[n], 16);
            s1l[n] += __shfl_xor(s1l[n], 32);
            s2l[n] += __shfl_xor(s2l[n], 16);
            s2l[n] += __shfl_xor(s2l[n], 32);
        }
        __syncthreads();
        float* red = (float*)lA;   // 512 floats used
        if (lg == 0) {
#pragma unroll
            for (int n = 0; n < 4; ++n) {
                int cidx = wc * 64 + n * 16 + ln;
                red[wr * 256 + cidx] = s1l[n];
                red[wr * 256 + 128 + cidx] = s2l[n];
            }
        }
        __syncthreads();
        if (t < 128) {
            atomicAdd(&s1g[bn + t], red[t] + red[256 + t]);
            atomicAdd(&s2g[bn + t], red[128 + t] + red[384 + t]);
        }
    } else {
        float scl[4], shf[4];
#pragma unroll
        for (int n = 0; n < 4; ++n) {
            scl[n] = scale[col0 + n * 16];
            shf[n] = shift[col0 + n * 16];
        }
#pragma unroll
        for (int m = 0; m < 4; ++m) {
#pragma unroll
            for (int r = 0; r < 4; ++r) {
                int row = bm + wr * 64 + m * 16 + lg * 4 + r;
                if (row >= M) continue;
                size_t base = (size_t)row * N;
#pragma unroll
                for (int n = 0; n < 4; ++n) {
                    size_t idx = base + col0 + n * 16;
                    float enc = fmaxf(acc[m][n][r] + bj[n], 0.f);
                    float yv = bf2f(Y[idx]);
                    float o = enc + fmaxf(__builtin_fmaf(yv, scl[n], shf[n]), 0.f);
                    if constexpr (MODE == 1) {
                        out_v[idx] = f2bf(enc);
                        ((unsigned short*)out0)[idx] = f2bf(o);
                    } else {
                        ((float*)out0)[idx] = o;
                    }
                }
            }
        }
    }
}

// ---------------------------------------------------------------------------

extern "C" void kernel_launch(void* const* d_in, const int* in_sizes, int n_in,
                              void* d_out, int out_size, void* d_ws, size_t ws_size,
                              hipStream_t stream) {
    const float* v   = (const float*)d_in[0];
    const int*   edg = (const int*)d_in[1];
    const float* We1 = (const float*)d_in[2];  const float* be1 = (const float*)d_in[3];
    const float* We2 = (const float*)d_in[4];  const float* be2 = (const float*)d_in[5];
    const float* We3 = (const float*)d_in[6];  const float* be3 = (const float*)d_in[7];
    const float* eps1 = (const float*)d_in[8];
    const float* W1 = (const float*)d_in[9];   const float* b1 = (const float*)d_in[10];
    const float* g1 = (const float*)d_in[11];  const float* bt1 = (const float*)d_in[12];
    const float* eps2 = (const float*)d_in[13];
    const float* W2 = (const float*)d_in[14];  const float* b2 = (const float*)d_in[15];
    const float* g2 = (const float*)d_in[16];  const float* bt2 = (const float*)d_in[17];
    const float* eps3 = (const float*)d_in[18];
    const float* W3 = (const float*)d_in[19];  const float* b3 = (const float*)d_in[20];
    const float* g3 = (const float*)d_in[21];  const float* bt3 = (const float*)d_in[22];

    const int M = in_sizes[0] / 86;
    const int E = in_sizes[1] / 2;
    const int* src = edg;
    const int* dst = edg + E;

    char* w = (char*)d_ws;
    auto carve = [&](size_t bytes) -> void* {
        void* p = (void*)w;
        w += (bytes + 255) & ~(size_t)255;
        return p;
    };
    int*   deg  = (int*)carve((size_t)M * 4);
    int*   off  = (int*)carve((size_t)(M + 1) * 4);
    int*   cur  = (int*)carve((size_t)M * 4);
    int*   srcs = (int*)carve((size_t)E * 4);
    int*   bsum = (int*)carve(1024 * 4);
    int*   boff = (int*)carve(1024 * 4);
    unsigned short* vbf = (unsigned short*)carve((size_t)M * 128 * 2);
    unsigned short* hb  = (unsigned short*)carve((size_t)M * 256 * 2);
    unsigned short* yb  = (unsigned short*)carve((size_t)M * 512 * 2);
    unsigned short* v1  = (unsigned short*)carve((size_t)M * 128 * 2);
    unsigned short* v2  = (unsigned short*)carve((size_t)M * 256 * 2);
    unsigned short* xv1 = (unsigned short*)carve((size_t)M * 128 * 2);
    unsigned short* xv2 = (unsigned short*)carve((size_t)M * 256 * 2);
    unsigned short* WT1g = (unsigned short*)carve(128 * 128 * 2);
    unsigned short* WT1e = (unsigned short*)carve(128 * 128 * 2);
    unsigned short* WT2g = (unsigned short*)carve(256 * 128 * 2);
    unsigned short* WT2e = (unsigned short*)carve(256 * 128 * 2);
    unsigned short* WT3g = (unsigned short*)carve(512 * 256 * 2);
    unsigned short* WT3e = (unsigned short*)carve(512 * 256 * 2);
    float* stats = (float*)carve(3 * 2048 * 4);  // per stage: s1,s2,scale,shift [512]

    hipMemsetAsync(deg, 0, (size_t)M * 4, stream);
    hipMemsetAsync(stats, 0, 3 * 2048 * 4, stream);

    // input conversion + weight prep
    conv_v_kernel<<<(M * 128 + 255) / 256, 256, 0, stream>>>(v, vbf, M);
    prep_wt_kernel<<<(128 * 128 + 255) / 256, 256, 0, stream>>>(W1, WT1g, 86, 128, 128);
    prep_wt_kernel<<<(128 * 128 + 255) / 256, 256, 0, stream>>>(We1, WT1e, 86, 128, 128);
    prep_wt_kernel<<<(256 * 128 + 255) / 256, 256, 0, stream>>>(W2, WT2g, 128, 256, 128);
    prep_wt_kernel<<<(256 * 128 + 255) / 256, 256, 0, stream>>>(We2, WT2e, 128, 256, 128);
    prep_wt_kernel<<<(512 * 256 + 255) / 256, 256, 0, stream>>>(W3, WT3g, 256, 512, 256);
    prep_wt_kernel<<<(512 * 256 + 255) / 256, 256, 0, stream>>>(We3, WT3e, 256, 512, 256);

    // CSR build (coalesced 3-kernel scan)
    const int NB = (M + 1023) / 1024;
    count_deg_kernel<<<(E + 255) / 256, 256, 0, stream>>>(dst, E, deg);
    scan_reduce_kernel<<<NB, 256, 0, stream>>>(deg, M, bsum);
    scan_bsum_kernel<<<1, 1024, 0, stream>>>(bsum, NB, boff, off, M);
    scan_apply_kernel<<<NB, 256, 0, stream>>>(deg, M, boff, off, cur);
    fill_kernel<<<(E + 255) / 256, 256, 0, stream>>>(src, dst, E, cur, srcs);

    const int MB = (M + 127) / 128;
    float* st;

    // ---------------- stage 1 (86(->128) -> 128) ----------------
    st = stats + 0 * 2048;
    gather_h_kernel<128><<<(M + 3) / 4, 256, 0, stream>>>(vbf, off, srcs, eps1, hb, M);
    mfma_gemm<128, 128, 0><<<dim3(1, MB), 256, 0, stream>>>(
        hb, WT1g, b1, nullptr, nullptr, nullptr, st, st + 512, yb, nullptr, M);
    finalize_kernel<<<1, 128, 0, stream>>>(st, st + 512, g1, bt1, M, 128, st + 1024, st + 1536);
    mfma_gemm<128, 128, 1><<<dim3(1, MB), 256, 0, stream>>>(
        vbf, WT1e, be1, yb, st + 1024, st + 1536, nullptr, nullptr, xv1, v1, M);

    // ---------------- stage 2 (128 -> 256) ----------------
    st = stats + 1 * 2048;
    gather_h_kernel<128><<<(M + 3) / 4, 256, 0, stream>>>(xv1, off, srcs, eps2, hb, M);
    mfma_gemm<128, 256, 0><<<dim3(2, MB), 256, 0, stream>>>(
        hb, WT2g, b2, nullptr, nullptr, nullptr, st, st + 512, yb, nullptr, M);
    finalize_kernel<<<2, 128, 0, stream>>>(st, st + 512, g2, bt2, M, 256, st + 1024, st + 1536);
    mfma_gemm<128, 256, 1><<<dim3(2, MB), 256, 0, stream>>>(
        v1, WT2e, be2, yb, st + 1024, st + 1536, nullptr, nullptr, xv2, v2, M);

    // ---------------- stage 3 (256 -> 512) ----------------
    st = stats + 2 * 2048;
    gather_h_kernel<256><<<(M + 3) / 4, 256, 0, stream>>>(xv2, off, srcs, eps3, hb, M);
    mfma_gemm<256, 512, 0><<<dim3(4, MB), 256, 0, stream>>>(
        hb, WT3g, b3, nullptr, nullptr, nullptr, st, st + 512, yb, nullptr, M);
    finalize_kernel<<<4, 128, 0, stream>>>(st, st + 512, g3, bt3, M, 512, st + 1024, st + 1536);
    mfma_gemm<256, 512, 2><<<dim3(4, MB), 256, 0, stream>>>(
        v2, WT3e, be3, yb, st + 1024, st + 1536, nullptr, nullptr, (float*)d_out, nullptr, M);
}

// Round 7
// 824.635 us; speedup vs baseline: 2.8866x; 1.1105x over previous
//
#include <hip/hip_runtime.h>

// ---------------------------------------------------------------------------
// GIN forward, bf16-MFMA version (resubmit after GPU-acquisition timeout).
// Round-6: (1) gather 4-way unrolled + 2 waves/node at D=256,
// (2) finalize folded into MODE1/2 GEMM prologue, prep kernels merged (17
// dispatches, was 25), (3) nontemporal d_out stores.
// ---------------------------------------------------------------------------

typedef short short8 __attribute__((ext_vector_type(8)));
typedef float f32x4 __attribute__((ext_vector_type(4)));

__device__ __forceinline__ unsigned short f2bf(float f) {
    unsigned int u = __float_as_uint(f);
    u = (u + 0x7fffu + ((u >> 16) & 1u)) >> 16;
    return (unsigned short)u;
}
__device__ __forceinline__ float bflo(unsigned int u) { return __uint_as_float(u << 16); }
__device__ __forceinline__ float bfhi(unsigned int u) { return __uint_as_float(u & 0xffff0000u); }
__device__ __forceinline__ unsigned int packbf2(float lo, float hi) {
    return (unsigned int)f2bf(lo) | ((unsigned int)f2bf(hi) << 16);
}
__device__ __forceinline__ float bf2f(unsigned short s) {
    return __uint_as_float(((unsigned int)s) << 16);
}

// async global->LDS, 16B per lane; dest = uniform base + lane*16 (HW rule)
__device__ __forceinline__ void gload16(const void* g, void* l) {
    __builtin_amdgcn_global_load_lds(
        (__attribute__((address_space(1))) const unsigned int*)g,
        (__attribute__((address_space(3))) unsigned int*)l, 16, 0, 0);
}

// ------------------------------- CSR build ---------------------------------

__global__ void count_deg_kernel(const int* __restrict__ dst, int E, int* __restrict__ deg) {
    int e = blockIdx.x * blockDim.x + threadIdx.x;
    if (e < E) atomicAdd(&deg[dst[e]], 1);
}

__global__ __launch_bounds__(256)
void scan_reduce_kernel(const int* __restrict__ deg, int M, int* __restrict__ bsum) {
    __shared__ int ws[4];
    int t = threadIdx.x;
    int i0 = blockIdx.x * 1024 + t * 4;
    int s = 0;
    if (i0 + 3 < M) {
        int4 v = *(const int4*)(deg + i0);
        s = v.x + v.y + v.z + v.w;
    } else {
        for (int i = i0; i < min(i0 + 4, M); ++i) s += deg[i];
    }
    for (int d = 1; d < 64; d <<= 1) s += __shfl_xor(s, d);
    if ((t & 63) == 0) ws[t >> 6] = s;
    __syncthreads();
    if (t == 0) bsum[blockIdx.x] = ws[0] + ws[1] + ws[2] + ws[3];
}

__global__ __launch_bounds__(1024)
void scan_bsum_kernel(const int* __restrict__ bsum, int NB,
                      int* __restrict__ boff, int* __restrict__ off, int M) {
    __shared__ int lds[1024];
    int t = threadIdx.x;
    int v = (t < NB) ? bsum[t] : 0;
    lds[t] = v;
    __syncthreads();
    for (int d = 1; d < 1024; d <<= 1) {
        int x = (t >= d) ? lds[t - d] : 0;
        __syncthreads();
        lds[t] += x;
        __syncthreads();
    }
    if (t < NB) boff[t] = lds[t] - v;
    if (t == NB - 1) off[M] = lds[t];
}

__global__ __launch_bounds__(256)
void scan_apply_kernel(const int* __restrict__ deg, int M, const int* __restrict__ boff,
                       int* __restrict__ off, int* __restrict__ cur) {
    __shared__ int lds[256];
    int t = threadIdx.x;
    int i0 = blockIdx.x * 1024 + t * 4;
    int d0 = 0, d1 = 0, d2 = 0, d3 = 0;
    if (i0 + 3 < M) {
        int4 v = *(const int4*)(deg + i0);
        d0 = v.x; d1 = v.y; d2 = v.z; d3 = v.w;
    } else {
        if (i0 + 0 < M) d0 = deg[i0 + 0];
        if (i0 + 1 < M) d1 = deg[i0 + 1];
        if (i0 + 2 < M) d2 = deg[i0 + 2];
        if (i0 + 3 < M) d3 = deg[i0 + 3];
    }
    int s = d0 + d1 + d2 + d3;
    lds[t] = s;
    __syncthreads();
    for (int d = 1; d < 256; d <<= 1) {
        int x = (t >= d) ? lds[t - d] : 0;
        __syncthreads();
        lds[t] += x;
        __syncthreads();
    }
    int e = lds[t] - s + boff[blockIdx.x];
    int e0 = e, e1 = e + d0, e2 = e1 + d1, e3 = e2 + d2;
    if (i0 + 3 < M) {
        *(int4*)(off + i0) = make_int4(e0, e1, e2, e3);
        *(int4*)(cur + i0) = make_int4(e0, e1, e2, e3);
    } else {
        if (i0 + 0 < M) { off[i0 + 0] = e0; cur[i0 + 0] = e0; }
        if (i0 + 1 < M) { off[i0 + 1] = e1; cur[i0 + 1] = e1; }
        if (i0 + 2 < M) { off[i0 + 2] = e2; cur[i0 + 2] = e2; }
        if (i0 + 3 < M) { off[i0 + 3] = e3; cur[i0 + 3] = e3; }
    }
}

__global__ void fill_kernel(const int* __restrict__ src, const int* __restrict__ dst, int E,
                            int* __restrict__ cur, int* __restrict__ srcs) {
    int e = blockIdx.x * blockDim.x + threadIdx.x;
    if (e < E) {
        int p = atomicAdd(&cur[dst[e]], 1);
        srcs[p] = src[e];
    }
}

// ------------------------- gather: h = (1+eps)x + segsum ---------------------
// WPN waves per node (D = WPN*128); each wave owns 64 uints (128 bf16) of the
// row. 4-way unrolled neighbor loop -> 4 independent loads in flight.
template <int WPN>
__global__ __launch_bounds__(256)
void gather_h_kernel(const unsigned short* __restrict__ x, const int* __restrict__ off,
                     const int* __restrict__ srcs, const float* __restrict__ epsp,
                     unsigned short* __restrict__ h, int M) {
    constexpr int RU = WPN * 64;   // uints per row
    int lane = threadIdx.x & 63;
    int gw = blockIdx.x * 4 + (threadIdx.x >> 6);
    int node = (WPN == 1) ? gw : (gw >> 1);
    int chunk = (WPN == 1) ? 0 : (gw & 1);
    if (node >= M) return;
    const unsigned int* xc = (const unsigned int*)x + chunk * 64 + lane;
    float ax = 0.f, ay = 0.f;
    int j0 = off[node], j1 = off[node + 1];
    int j = j0;
    for (; j + 3 < j1; j += 4) {
        int s0 = srcs[j + 0], s1 = srcs[j + 1], s2 = srcs[j + 2], s3 = srcs[j + 3];
        unsigned int u0 = xc[(size_t)s0 * RU];
        unsigned int u1 = xc[(size_t)s1 * RU];
        unsigned int u2 = xc[(size_t)s2 * RU];
        unsigned int u3 = xc[(size_t)s3 * RU];
        ax += bflo(u0); ay += bfhi(u0);
        ax += bflo(u1); ay += bfhi(u1);
        ax += bflo(u2); ay += bfhi(u2);
        ax += bflo(u3); ay += bfhi(u3);
    }
    for (; j < j1; ++j) {
        unsigned int u = xc[(size_t)srcs[j] * RU];
        ax += bflo(u); ay += bfhi(u);
    }
    float e = 1.0f + epsp[0];
    unsigned int su = xc[(size_t)node * RU];
    ((unsigned int*)h)[(size_t)node * RU + chunk * 64 + lane] =
        packbf2(__builtin_fmaf(e, bflo(su), ax), __builtin_fmaf(e, bfhi(su), ay));
}

// --------------------- prep: v->vbf(pad128) + 6x W->WT bf16 ------------------
__device__ __forceinline__ void wt_fill(const float* __restrict__ W, unsigned short* __restrict__ WT,
                                        int id, int K, int N, int KpShift) {
    int n = id >> KpShift, k = id & ((1 << KpShift) - 1);
    float v = (k < K) ? W[(size_t)k * N + n] : 0.f;
    WT[id] = f2bf(v);
}

__global__ void prep_all_kernel(const float* __restrict__ v, unsigned short* __restrict__ vbf,
                                const float* __restrict__ W1, const float* __restrict__ We1,
                                unsigned short* __restrict__ WT1g, unsigned short* __restrict__ WT1e,
                                const float* __restrict__ W2, const float* __restrict__ We2,
                                unsigned short* __restrict__ WT2g, unsigned short* __restrict__ WT2e,
                                const float* __restrict__ W3, const float* __restrict__ We3,
                                unsigned short* __restrict__ WT3g, unsigned short* __restrict__ WT3e,
                                int M) {
    int id = blockIdx.x * 256 + threadIdx.x;
    int nv = M * 128;
    if (id < nv) {
        int r = id >> 7, k = id & 127;
        float x = (k < 86) ? v[(size_t)r * 86 + k] : 0.f;
        vbf[id] = f2bf(x);
        return;
    }
    id -= nv;
    if (id < 16384) { wt_fill(W1, WT1g, id, 86, 128, 7); return; }
    id -= 16384;
    if (id < 16384) { wt_fill(We1, WT1e, id, 86, 128, 7); return; }
    id -= 16384;
    if (id < 32768) { wt_fill(W2, WT2g, id, 128, 256, 7); return; }
    id -= 32768;
    if (id < 32768) { wt_fill(We2, WT2e, id, 128, 256, 7); return; }
    id -= 32768;
    if (id < 131072) { wt_fill(W3, WT3g, id, 256, 512, 8); return; }
    id -= 131072;
    if (id < 131072) { wt_fill(We3, WT3e, id, 256, 512, 8); return; }
}

// ------------------------------ MFMA GEMM -----------------------------------
// BM=BN=128, BK=64, 256 threads (4 waves, 2x2 of 64x64), 16x16x32 bf16 MFMA.
// MODE 0: yb(bf16) = A@B + bias; fused fp32 per-column sum/sumsq atomics.
// MODE 1: scale/shift computed in-prologue from s1/s2/g/bt;
//         enc = relu(A@B+bias) -> out_v (bf16); out0(bf16) = enc + relu(bn(Y))
// MODE 2: like MODE 1 but out0 = fp32 (nontemporal), no out_v.
template <int Kp, int N, int MODE>
__global__ __launch_bounds__(256, 2)
void mfma_gemm(const unsigned short* __restrict__ A, const unsigned short* __restrict__ WT,
               const float* __restrict__ bias,
               const unsigned short* __restrict__ Y,
               float* __restrict__ s1g, float* __restrict__ s2g,
               const float* __restrict__ gam, const float* __restrict__ bet,
               void* __restrict__ out0, unsigned short* __restrict__ out_v, int M) {
    constexpr int BK = 64;
    __shared__ unsigned short lA[128 * BK];
    __shared__ unsigned short lB[128 * BK];
    const int t = threadIdx.x;
    const int l = t & 63, w = t >> 6;
    const int wr = w >> 1, wc = w & 1;
    const int bm = blockIdx.y * 128, bn = blockIdx.x * 128;
    const int ln = l & 15, lg = l >> 4;

    f32x4 acc[4][4] = {};

    const int col0 = bn + wc * 64 + ln;   // + n*16
    float scl[4], shf[4];
    if constexpr (MODE != 0) {
        float inv = 1.0f / (float)M;
#pragma unroll
        for (int n = 0; n < 4; ++n) {
            int c = col0 + n * 16;
            float mean = s1g[c] * inv;
            float var = s2g[c] * inv - mean * mean;
            float sc = gam[c] * rsqrtf(var + 1e-5f);
            scl[n] = sc;
            shf[n] = __builtin_fmaf(-mean, sc, bet[c]);
        }
    }

    const int srow0 = w * 32;           // this wave stages rows [srow0, srow0+32)
    const int srow = srow0 + (l >> 3);  // + i*8 per instruction
    const int sc8 = l & 7;              // 16B chunk slot this lane fills

    for (int k0 = 0; k0 < Kp; k0 += BK) {
#pragma unroll
        for (int i = 0; i < 4; ++i) {
            int row = srow + i * 8;
            int gc = sc8 ^ (row & 7);   // pre-swizzled global chunk
            int gra = bm + row;
            gra = gra < M ? gra : M - 1;
            gload16(A + (size_t)gra * Kp + k0 + gc * 8, &lA[(srow0 + i * 8) * BK]);
            gload16(WT + (size_t)(bn + row) * Kp + k0 + gc * 8, &lB[(srow0 + i * 8) * BK]);
        }
        __syncthreads();
#pragma unroll
        for (int ks = 0; ks < 2; ++ks) {
            short8 af[4], bfr[4];
#pragma unroll
            for (int m = 0; m < 4; ++m) {
                int row = wr * 64 + m * 16 + ln;
                int g = ks * 4 + lg;
                af[m] = *(const short8*)&lA[row * BK + ((g ^ (row & 7)) * 8)];
            }
#pragma unroll
            for (int n = 0; n < 4; ++n) {
                int row = wc * 64 + n * 16 + ln;
                int g = ks * 4 + lg;
                bfr[n] = *(const short8*)&lB[row * BK + ((g ^ (row & 7)) * 8)];
            }
#pragma unroll
            for (int m = 0; m < 4; ++m)
#pragma unroll
                for (int n = 0; n < 4; ++n)
                    acc[m][n] = __builtin_amdgcn_mfma_f32_16x16x32_bf16(af[m], bfr[n], acc[m][n], 0, 0, 0);
        }
        __syncthreads();
    }

    // ---- epilogue ----
    float bj[4];
#pragma unroll
    for (int n = 0; n < 4; ++n) bj[n] = bias[col0 + n * 16];

    if constexpr (MODE == 0) {
        unsigned short* outp = (unsigned short*)out0;
        float s1l[4] = {0.f, 0.f, 0.f, 0.f}, s2l[4] = {0.f, 0.f, 0.f, 0.f};
#pragma unroll
        for (int m = 0; m < 4; ++m) {
#pragma unroll
            for (int r = 0; r < 4; ++r) {
                int row = bm + wr * 64 + m * 16 + lg * 4 + r;
                if (row < M) {
                    size_t base = (size_t)row * N;
#pragma unroll
                    for (int n = 0; n < 4; ++n) {
                        float y = acc[m][n][r] + bj[n];
                        outp[base + col0 + n * 16] = f2bf(y);
                        s1l[n] += y;
                        s2l[n] = __builtin_fmaf(y, y, s2l[n]);
                    }
                }
            }
        }
#pragma unroll
        for (int n = 0; n < 4; ++n) {
            s1l[n] += __shfl_xor(s1l[n], 16);
            s1l[n] += __shfl_xor(s1l[n], 32);
            s2l[n] += __shfl_xor(s2l[n], 16);
            s2l[n] += __shfl_xor(s2l[n], 32);
        }
        __syncthreads();
        float* red = (float*)lA;   // 512 floats used
        if (lg == 0) {
#pragma unroll
            for (int n = 0; n < 4; ++n) {
                int cidx = wc * 64 + n * 16 + ln;
                red[wr * 256 + cidx] = s1l[n];
                red[wr * 256 + 128 + cidx] = s2l[n];
            }
        }
        __syncthreads();
        if (t < 128) {
            atomicAdd(&s1g[bn + t], red[t] + red[256 + t]);
            atomicAdd(&s2g[bn + t], red[128 + t] + red[384 + t]);
        }
    } else {
#pragma unroll
        for (int m = 0; m < 4; ++m) {
#pragma unroll
            for (int r = 0; r < 4; ++r) {
                int row = bm + wr * 64 + m * 16 + lg * 4 + r;
                if (row >= M) continue;
                size_t base = (size_t)row * N;
#pragma unroll
                for (int n = 0; n < 4; ++n) {
                    size_t idx = base + col0 + n * 16;
                    float enc = fmaxf(acc[m][n][r] + bj[n], 0.f);
                    float yv = bf2f(Y[idx]);
                    float o = enc + fmaxf(__builtin_fmaf(yv, scl[n], shf[n]), 0.f);
                    if constexpr (MODE == 1) {
                        out_v[idx] = f2bf(enc);
                        ((unsigned short*)out0)[idx] = f2bf(o);
                    } else {
                        __builtin_nontemporal_store(o, &((float*)out0)[idx]);
                    }
                }
            }
        }
    }
}

// ---------------------------------------------------------------------------

extern "C" void kernel_launch(void* const* d_in, const int* in_sizes, int n_in,
                              void* d_out, int out_size, void* d_ws, size_t ws_size,
                              hipStream_t stream) {
    const float* v   = (const float*)d_in[0];
    const int*   edg = (const int*)d_in[1];
    const float* We1 = (const float*)d_in[2];  const float* be1 = (const float*)d_in[3];
    const float* We2 = (const float*)d_in[4];  const float* be2 = (const float*)d_in[5];
    const float* We3 = (const float*)d_in[6];  const float* be3 = (const float*)d_in[7];
    const float* eps1 = (const float*)d_in[8];
    const float* W1 = (const float*)d_in[9];   const float* b1 = (const float*)d_in[10];
    const float* g1 = (const float*)d_in[11];  const float* bt1 = (const float*)d_in[12];
    const float* eps2 = (const float*)d_in[13];
    const float* W2 = (const float*)d_in[14];  const float* b2 = (const float*)d_in[15];
    const float* g2 = (const float*)d_in[16];  const float* bt2 = (const float*)d_in[17];
    const float* eps3 = (const float*)d_in[18];
    const float* W3 = (const float*)d_in[19];  const float* b3 = (const float*)d_in[20];
    const float* g3 = (const float*)d_in[21];  const float* bt3 = (const float*)d_in[22];

    const int M = in_sizes[0] / 86;
    const int E = in_sizes[1] / 2;
    const int* src = edg;
    const int* dst = edg + E;

    char* w = (char*)d_ws;
    auto carve = [&](size_t bytes) -> void* {
        void* p = (void*)w;
        w += (bytes + 255) & ~(size_t)255;
        return p;
    };
    int*   deg  = (int*)carve((size_t)M * 4);
    int*   off  = (int*)carve((size_t)(M + 1) * 4);
    int*   cur  = (int*)carve((size_t)M * 4);
    int*   srcs = (int*)carve((size_t)E * 4);
    int*   bsum = (int*)carve(1024 * 4);
    int*   boff = (int*)carve(1024 * 4);
    unsigned short* vbf = (unsigned short*)carve((size_t)M * 128 * 2);
    unsigned short* hb  = (unsigned short*)carve((size_t)M * 256 * 2);
    unsigned short* yb  = (unsigned short*)carve((size_t)M * 512 * 2);
    unsigned short* v1  = (unsigned short*)carve((size_t)M * 128 * 2);
    unsigned short* v2  = (unsigned short*)carve((size_t)M * 256 * 2);
    unsigned short* xv1 = (unsigned short*)carve((size_t)M * 128 * 2);
    unsigned short* xv2 = (unsigned short*)carve((size_t)M * 256 * 2);
    unsigned short* WT1g = (unsigned short*)carve(128 * 128 * 2);
    unsigned short* WT1e = (unsigned short*)carve(128 * 128 * 2);
    unsigned short* WT2g = (unsigned short*)carve(256 * 128 * 2);
    unsigned short* WT2e = (unsigned short*)carve(256 * 128 * 2);
    unsigned short* WT3g = (unsigned short*)carve(512 * 256 * 2);
    unsigned short* WT3e = (unsigned short*)carve(512 * 256 * 2);
    float* stats = (float*)carve(3 * 1024 * 4);  // per stage: s1[512], s2[512]

    hipMemsetAsync(deg, 0, (size_t)M * 4, stream);
    hipMemsetAsync(stats, 0, 3 * 1024 * 4, stream);

    // input conversion + weight prep (single kernel)
    {
        int total = M * 128 + 2 * (16384 + 32768 + 131072);
        prep_all_kernel<<<(total + 255) / 256, 256, 0, stream>>>(
            v, vbf, W1, We1, WT1g, WT1e, W2, We2, WT2g, WT2e, W3, We3, WT3g, WT3e, M);
    }

    // CSR build (coalesced 3-kernel scan)
    const int NB = (M + 1023) / 1024;
    count_deg_kernel<<<(E + 255) / 256, 256, 0, stream>>>(dst, E, deg);
    scan_reduce_kernel<<<NB, 256, 0, stream>>>(deg, M, bsum);
    scan_bsum_kernel<<<1, 1024, 0, stream>>>(bsum, NB, boff, off, M);
    scan_apply_kernel<<<NB, 256, 0, stream>>>(deg, M, boff, off, cur);
    fill_kernel<<<(E + 255) / 256, 256, 0, stream>>>(src, dst, E, cur, srcs);

    const int MB = (M + 127) / 128;
    float* st;

    // ---------------- stage 1 (86(->128) -> 128) ----------------
    st = stats + 0 * 1024;
    gather_h_kernel<1><<<(M + 3) / 4, 256, 0, stream>>>(vbf, off, srcs, eps1, hb, M);
    mfma_gemm<128, 128, 0><<<dim3(1, MB), 256, 0, stream>>>(
        hb, WT1g, b1, nullptr, st, st + 512, nullptr, nullptr, yb, nullptr, M);
    mfma_gemm<128, 128, 1><<<dim3(1, MB), 256, 0, stream>>>(
        vbf, WT1e, be1, yb, st, st + 512, g1, bt1, xv1, v1, M);

    // ---------------- stage 2 (128 -> 256) ----------------
    st = stats + 1 * 1024;
    gather_h_kernel<1><<<(M + 3) / 4, 256, 0, stream>>>(xv1, off, srcs, eps2, hb, M);
    mfma_gemm<128, 256, 0><<<dim3(2, MB), 256, 0, stream>>>(
        hb, WT2g, b2, nullptr, st, st + 512, nullptr, nullptr, yb, nullptr, M);
    mfma_gemm<128, 256, 1><<<dim3(2, MB), 256, 0, stream>>>(
        v1, WT2e, be2, yb, st, st + 512, g2, bt2, xv2, v2, M);

    // ---------------- stage 3 (256 -> 512) ----------------
    st = stats + 2 * 1024;
    gather_h_kernel<2><<<(2 * M + 3) / 4, 256, 0, stream>>>(xv2, off, srcs, eps3, hb, M);
    mfma_gemm<256, 512, 0><<<dim3(4, MB), 256, 0, stream>>>(
        hb, WT3g, b3, nullptr, st, st + 512, nullptr, nullptr, yb, nullptr, M);
    mfma_gemm<256, 512, 2><<<dim3(4, MB), 256, 0, stream>>>(
        v2, WT3e, be3, yb, st, st + 512, g3, bt3, (float*)d_out, nullptr, M);
}

// Round 8
// 801.603 us; speedup vs baseline: 2.9695x; 1.0287x over previous
//
#include <hip/hip_runtime.h>

// ---------------------------------------------------------------------------
// GIN forward, bf16-MFMA version.
// Round-8: yb (pre-BN y) stored in fragment-tiled layout (ushort4 per lane,
// per-wave-contiguous) -> fully coalesced write (MODE0) + read (MODE1/2).
// Previously 32B-segment scalar bf16 access, ~358 MB of poorly-coalesced
// traffic across the 3 stages.
// ---------------------------------------------------------------------------

typedef short short8 __attribute__((ext_vector_type(8)));
typedef float f32x4 __attribute__((ext_vector_type(4)));
typedef unsigned short ushort4v __attribute__((ext_vector_type(4)));

__device__ __forceinline__ unsigned short f2bf(float f) {
    unsigned int u = __float_as_uint(f);
    u = (u + 0x7fffu + ((u >> 16) & 1u)) >> 16;
    return (unsigned short)u;
}
__device__ __forceinline__ float bflo(unsigned int u) { return __uint_as_float(u << 16); }
__device__ __forceinline__ float bfhi(unsigned int u) { return __uint_as_float(u & 0xffff0000u); }
__device__ __forceinline__ unsigned int packbf2(float lo, float hi) {
    return (unsigned int)f2bf(lo) | ((unsigned int)f2bf(hi) << 16);
}
__device__ __forceinline__ float bf2f(unsigned short s) {
    return __uint_as_float(((unsigned int)s) << 16);
}

// async global->LDS, 16B per lane; dest = uniform base + lane*16 (HW rule)
__device__ __forceinline__ void gload16(const void* g, void* l) {
    __builtin_amdgcn_global_load_lds(
        (__attribute__((address_space(1))) const unsigned int*)g,
        (__attribute__((address_space(3))) unsigned int*)l, 16, 0, 0);
}

// ------------------------------- CSR build ---------------------------------

__global__ void count_deg_kernel(const int* __restrict__ dst, int E, int* __restrict__ deg) {
    int e = blockIdx.x * blockDim.x + threadIdx.x;
    if (e < E) atomicAdd(&deg[dst[e]], 1);
}

__global__ __launch_bounds__(256)
void scan_reduce_kernel(const int* __restrict__ deg, int M, int* __restrict__ bsum) {
    __shared__ int ws[4];
    int t = threadIdx.x;
    int i0 = blockIdx.x * 1024 + t * 4;
    int s = 0;
    if (i0 + 3 < M) {
        int4 v = *(const int4*)(deg + i0);
        s = v.x + v.y + v.z + v.w;
    } else {
        for (int i = i0; i < min(i0 + 4, M); ++i) s += deg[i];
    }
    for (int d = 1; d < 64; d <<= 1) s += __shfl_xor(s, d);
    if ((t & 63) == 0) ws[t >> 6] = s;
    __syncthreads();
    if (t == 0) bsum[blockIdx.x] = ws[0] + ws[1] + ws[2] + ws[3];
}

__global__ __launch_bounds__(1024)
void scan_bsum_kernel(const int* __restrict__ bsum, int NB,
                      int* __restrict__ boff, int* __restrict__ off, int M) {
    __shared__ int lds[1024];
    int t = threadIdx.x;
    int v = (t < NB) ? bsum[t] : 0;
    lds[t] = v;
    __syncthreads();
    for (int d = 1; d < 1024; d <<= 1) {
        int x = (t >= d) ? lds[t - d] : 0;
        __syncthreads();
        lds[t] += x;
        __syncthreads();
    }
    if (t < NB) boff[t] = lds[t] - v;
    if (t == NB - 1) off[M] = lds[t];
}

__global__ __launch_bounds__(256)
void scan_apply_kernel(const int* __restrict__ deg, int M, const int* __restrict__ boff,
                       int* __restrict__ off, int* __restrict__ cur) {
    __shared__ int lds[256];
    int t = threadIdx.x;
    int i0 = blockIdx.x * 1024 + t * 4;
    int d0 = 0, d1 = 0, d2 = 0, d3 = 0;
    if (i0 + 3 < M) {
        int4 v = *(const int4*)(deg + i0);
        d0 = v.x; d1 = v.y; d2 = v.z; d3 = v.w;
    } else {
        if (i0 + 0 < M) d0 = deg[i0 + 0];
        if (i0 + 1 < M) d1 = deg[i0 + 1];
        if (i0 + 2 < M) d2 = deg[i0 + 2];
        if (i0 + 3 < M) d3 = deg[i0 + 3];
    }
    int s = d0 + d1 + d2 + d3;
    lds[t] = s;
    __syncthreads();
    for (int d = 1; d < 256; d <<= 1) {
        int x = (t >= d) ? lds[t - d] : 0;
        __syncthreads();
        lds[t] += x;
        __syncthreads();
    }
    int e = lds[t] - s + boff[blockIdx.x];
    int e0 = e, e1 = e + d0, e2 = e1 + d1, e3 = e2 + d2;
    if (i0 + 3 < M) {
        *(int4*)(off + i0) = make_int4(e0, e1, e2, e3);
        *(int4*)(cur + i0) = make_int4(e0, e1, e2, e3);
    } else {
        if (i0 + 0 < M) { off[i0 + 0] = e0; cur[i0 + 0] = e0; }
        if (i0 + 1 < M) { off[i0 + 1] = e1; cur[i0 + 1] = e1; }
        if (i0 + 2 < M) { off[i0 + 2] = e2; cur[i0 + 2] = e2; }
        if (i0 + 3 < M) { off[i0 + 3] = e3; cur[i0 + 3] = e3; }
    }
}

__global__ void fill_kernel(const int* __restrict__ src, const int* __restrict__ dst, int E,
                            int* __restrict__ cur, int* __restrict__ srcs) {
    int e = blockIdx.x * blockDim.x + threadIdx.x;
    if (e < E) {
        int p = atomicAdd(&cur[dst[e]], 1);
        srcs[p] = src[e];
    }
}

// ------------------------- gather: h = (1+eps)x + segsum ---------------------
// WPN waves per node (D = WPN*128); each wave owns 64 uints (128 bf16) of the
// row. 4-way unrolled neighbor loop -> 4 independent loads in flight.
template <int WPN>
__global__ __launch_bounds__(256)
void gather_h_kernel(const unsigned short* __restrict__ x, const int* __restrict__ off,
                     const int* __restrict__ srcs, const float* __restrict__ epsp,
                     unsigned short* __restrict__ h, int M) {
    constexpr int RU = WPN * 64;   // uints per row
    int lane = threadIdx.x & 63;
    int gw = blockIdx.x * 4 + (threadIdx.x >> 6);
    int node = (WPN == 1) ? gw : (gw >> 1);
    int chunk = (WPN == 1) ? 0 : (gw & 1);
    if (node >= M) return;
    const unsigned int* xc = (const unsigned int*)x + chunk * 64 + lane;
    float ax = 0.f, ay = 0.f;
    int j0 = off[node], j1 = off[node + 1];
    int j = j0;
    for (; j + 3 < j1; j += 4) {
        int s0 = srcs[j + 0], s1 = srcs[j + 1], s2 = srcs[j + 2], s3 = srcs[j + 3];
        unsigned int u0 = xc[(size_t)s0 * RU];
        unsigned int u1 = xc[(size_t)s1 * RU];
        unsigned int u2 = xc[(size_t)s2 * RU];
        unsigned int u3 = xc[(size_t)s3 * RU];
        ax += bflo(u0); ay += bfhi(u0);
        ax += bflo(u1); ay += bfhi(u1);
        ax += bflo(u2); ay += bfhi(u2);
        ax += bflo(u3); ay += bfhi(u3);
    }
    for (; j < j1; ++j) {
        unsigned int u = xc[(size_t)srcs[j] * RU];
        ax += bflo(u); ay += bfhi(u);
    }
    float e = 1.0f + epsp[0];
    unsigned int su = xc[(size_t)node * RU];
    ((unsigned int*)h)[(size_t)node * RU + chunk * 64 + lane] =
        packbf2(__builtin_fmaf(e, bflo(su), ax), __builtin_fmaf(e, bfhi(su), ay));
}

// --------------------- prep: v->vbf(pad128) + 6x W->WT bf16 ------------------
__device__ __forceinline__ void wt_fill(const float* __restrict__ W, unsigned short* __restrict__ WT,
                                        int id, int K, int N, int KpShift) {
    int n = id >> KpShift, k = id & ((1 << KpShift) - 1);
    float v = (k < K) ? W[(size_t)k * N + n] : 0.f;
    WT[id] = f2bf(v);
}

__global__ void prep_all_kernel(const float* __restrict__ v, unsigned short* __restrict__ vbf,
                                const float* __restrict__ W1, const float* __restrict__ We1,
                                unsigned short* __restrict__ WT1g, unsigned short* __restrict__ WT1e,
                                const float* __restrict__ W2, const float* __restrict__ We2,
                                unsigned short* __restrict__ WT2g, unsigned short* __restrict__ WT2e,
                                const float* __restrict__ W3, const float* __restrict__ We3,
                                unsigned short* __restrict__ WT3g, unsigned short* __restrict__ WT3e,
                                int M) {
    int id = blockIdx.x * 256 + threadIdx.x;
    int nv = M * 128;
    if (id < nv) {
        int r = id >> 7, k = id & 127;
        float x = (k < 86) ? v[(size_t)r * 86 + k] : 0.f;
        vbf[id] = f2bf(x);
        return;
    }
    id -= nv;
    if (id < 16384) { wt_fill(W1, WT1g, id, 86, 128, 7); return; }
    id -= 16384;
    if (id < 16384) { wt_fill(We1, WT1e, id, 86, 128, 7); return; }
    id -= 16384;
    if (id < 32768) { wt_fill(W2, WT2g, id, 128, 256, 7); return; }
    id -= 32768;
    if (id < 32768) { wt_fill(We2, WT2e, id, 128, 256, 7); return; }
    id -= 32768;
    if (id < 131072) { wt_fill(W3, WT3g, id, 256, 512, 8); return; }
    id -= 131072;
    if (id < 131072) { wt_fill(We3, WT3e, id, 256, 512, 8); return; }
}

// ------------------------------ MFMA GEMM -----------------------------------
// BM=BN=128, BK=64, 256 threads (4 waves, 2x2 of 64x64), 16x16x32 bf16 MFMA.
// yb uses a fragment-tiled layout (shared by MODE0 writer and MODE1/2 reader):
//   yb4[((tile*4 + w)*16 + m*4 + n)*64 + lane]  (ushort4 = r0..r3)
// where tile = blockIdx.y*gridDim.x + blockIdx.x — grids of the MODE0/MODE1
// pair are identical per stage, so the mapping is consistent.
// MODE 0: yb(bf16, tiled) = A@B + bias; fused fp32 per-column sum/sumsq atomics.
// MODE 1: scale/shift from s1/s2/g/bt in-prologue;
//         enc = relu(A@B+bias) -> out_v (bf16); out0(bf16) = enc + relu(bn(Y))
// MODE 2: like MODE 1 but out0 = fp32 (nontemporal), no out_v.
template <int Kp, int N, int MODE>
__global__ __launch_bounds__(256, 2)
void mfma_gemm(const unsigned short* __restrict__ A, const unsigned short* __restrict__ WT,
               const float* __restrict__ bias,
               const ushort4v* __restrict__ Y4,
               float* __restrict__ s1g, float* __restrict__ s2g,
               const float* __restrict__ gam, const float* __restrict__ bet,
               void* __restrict__ out0, unsigned short* __restrict__ out_v, int M) {
    constexpr int BK = 64;
    __shared__ unsigned short lA[128 * BK];
    __shared__ unsigned short lB[128 * BK];
    const int t = threadIdx.x;
    const int l = t & 63, w = t >> 6;
    const int wr = w >> 1, wc = w & 1;
    const int bm = blockIdx.y * 128, bn = blockIdx.x * 128;
    const int ln = l & 15, lg = l >> 4;
    const size_t tilew = (size_t)(blockIdx.y * gridDim.x + blockIdx.x) * 4 + w;

    f32x4 acc[4][4] = {};

    const int col0 = bn + wc * 64 + ln;   // + n*16
    float scl[4], shf[4];
    if constexpr (MODE != 0) {
        float inv = 1.0f / (float)M;
#pragma unroll
        for (int n = 0; n < 4; ++n) {
            int c = col0 + n * 16;
            float mean = s1g[c] * inv;
            float var = s2g[c] * inv - mean * mean;
            float sc = gam[c] * rsqrtf(var + 1e-5f);
            scl[n] = sc;
            shf[n] = __builtin_fmaf(-mean, sc, bet[c]);
        }
    }

    const int srow0 = w * 32;           // this wave stages rows [srow0, srow0+32)
    const int srow = srow0 + (l >> 3);  // + i*8 per instruction
    const int sc8 = l & 7;              // 16B chunk slot this lane fills

    for (int k0 = 0; k0 < Kp; k0 += BK) {
#pragma unroll
        for (int i = 0; i < 4; ++i) {
            int row = srow + i * 8;
            int gc = sc8 ^ (row & 7);   // pre-swizzled global chunk
            int gra = bm + row;
            gra = gra < M ? gra : M - 1;
            gload16(A + (size_t)gra * Kp + k0 + gc * 8, &lA[(srow0 + i * 8) * BK]);
            gload16(WT + (size_t)(bn + row) * Kp + k0 + gc * 8, &lB[(srow0 + i * 8) * BK]);
        }
        __syncthreads();
#pragma unroll
        for (int ks = 0; ks < 2; ++ks) {
            short8 af[4], bfr[4];
#pragma unroll
            for (int m = 0; m < 4; ++m) {
                int row = wr * 64 + m * 16 + ln;
                int g = ks * 4 + lg;
                af[m] = *(const short8*)&lA[row * BK + ((g ^ (row & 7)) * 8)];
            }
#pragma unroll
            for (int n = 0; n < 4; ++n) {
                int row = wc * 64 + n * 16 + ln;
                int g = ks * 4 + lg;
                bfr[n] = *(const short8*)&lB[row * BK + ((g ^ (row & 7)) * 8)];
            }
#pragma unroll
            for (int m = 0; m < 4; ++m)
#pragma unroll
                for (int n = 0; n < 4; ++n)
                    acc[m][n] = __builtin_amdgcn_mfma_f32_16x16x32_bf16(af[m], bfr[n], acc[m][n], 0, 0, 0);
        }
        __syncthreads();
    }

    // ---- epilogue ----
    float bj[4];
#pragma unroll
    for (int n = 0; n < 4; ++n) bj[n] = bias[col0 + n * 16];

    if constexpr (MODE == 0) {
        ushort4v* out4 = (ushort4v*)out0;
        float s1l[4] = {0.f, 0.f, 0.f, 0.f}, s2l[4] = {0.f, 0.f, 0.f, 0.f};
#pragma unroll
        for (int m = 0; m < 4; ++m) {
#pragma unroll
            for (int n = 0; n < 4; ++n) {
                ushort4v pk;
#pragma unroll
                for (int r = 0; r < 4; ++r) {
                    float y = acc[m][n][r] + bj[n];
                    pk[r] = f2bf(y);
                    int row = bm + wr * 64 + m * 16 + lg * 4 + r;
                    if (row < M) {
                        s1l[n] += y;
                        s2l[n] = __builtin_fmaf(y, y, s2l[n]);
                    }
                }
                out4[(tilew * 16 + m * 4 + n) * 64 + l] = pk;   // 512B/wave, coalesced
            }
        }
#pragma unroll
        for (int n = 0; n < 4; ++n) {
            s1l[n] += __shfl_xor(s1l[n], 16);
            s1l[n] += __shfl_xor(s1l[n], 32);
            s2l[n] += __shfl_xor(s2l[n], 16);
            s2l[n] += __shfl_xor(s2l[n], 32);
        }
        __syncthreads();
        float* red = (float*)lA;   // 512 floats used
        if (lg == 0) {
#pragma unroll
            for (int n = 0; n < 4; ++n) {
                int cidx = wc * 64 + n * 16 + ln;
                red[wr * 256 + cidx] = s1l[n];
                red[wr * 256 + 128 + cidx] = s2l[n];
            }
        }
        __syncthreads();
        if (t < 128) {
            atomicAdd(&s1g[bn + t], red[t] + red[256 + t]);
            atomicAdd(&s2g[bn + t], red[128 + t] + red[384 + t]);
        }
    } else {
#pragma unroll
        for (int m = 0; m < 4; ++m) {
            ushort4v yv4[4];
#pragma unroll
            for (int n = 0; n < 4; ++n)
                yv4[n] = Y4[(tilew * 16 + m * 4 + n) * 64 + l];   // coalesced read
#pragma unroll
            for (int r = 0; r < 4; ++r) {
                int row = bm + wr * 64 + m * 16 + lg * 4 + r;
                if (row >= M) continue;
                size_t base = (size_t)row * N;
#pragma unroll
                for (int n = 0; n < 4; ++n) {
                    size_t idx = base + col0 + n * 16;
                    float enc = fmaxf(acc[m][n][r] + bj[n], 0.f);
                    float yv = bf2f(yv4[n][r]);
                    float o = enc + fmaxf(__builtin_fmaf(yv, scl[n], shf[n]), 0.f);
                    if constexpr (MODE == 1) {
                        out_v[idx] = f2bf(enc);
                        ((unsigned short*)out0)[idx] = f2bf(o);
                    } else {
                        __builtin_nontemporal_store(o, &((float*)out0)[idx]);
                    }
                }
            }
        }
    }
}

// ---------------------------------------------------------------------------

extern "C" void kernel_launch(void* const* d_in, const int* in_sizes, int n_in,
                              void* d_out, int out_size, void* d_ws, size_t ws_size,
                              hipStream_t stream) {
    const float* v   = (const float*)d_in[0];
    const int*   edg = (const int*)d_in[1];
    const float* We1 = (const float*)d_in[2];  const float* be1 = (const float*)d_in[3];
    const float* We2 = (const float*)d_in[4];  const float* be2 = (const float*)d_in[5];
    const float* We3 = (const float*)d_in[6];  const float* be3 = (const float*)d_in[7];
    const float* eps1 = (const float*)d_in[8];
    const float* W1 = (const float*)d_in[9];   const float* b1 = (const float*)d_in[10];
    const float* g1 = (const float*)d_in[11];  const float* bt1 = (const float*)d_in[12];
    const float* eps2 = (const float*)d_in[13];
    const float* W2 = (const float*)d_in[14];  const float* b2 = (const float*)d_in[15];
    const float* g2 = (const float*)d_in[16];  const float* bt2 = (const float*)d_in[17];
    const float* eps3 = (const float*)d_in[18];
    const float* W3 = (const float*)d_in[19];  const float* b3 = (const float*)d_in[20];
    const float* g3 = (const float*)d_in[21];  const float* bt3 = (const float*)d_in[22];

    const int M = in_sizes[0] / 86;
    const int E = in_sizes[1] / 2;
    const int* src = edg;
    const int* dst = edg + E;

    char* w = (char*)d_ws;
    auto carve = [&](size_t bytes) -> void* {
        void* p = (void*)w;
        w += (bytes + 255) & ~(size_t)255;
        return p;
    };
    const int MB = (M + 127) / 128;
    int*   deg  = (int*)carve((size_t)M * 4);
    int*   off  = (int*)carve((size_t)(M + 1) * 4);
    int*   cur  = (int*)carve((size_t)M * 4);
    int*   srcs = (int*)carve((size_t)E * 4);
    int*   bsum = (int*)carve(1024 * 4);
    int*   boff = (int*)carve(1024 * 4);
    unsigned short* vbf = (unsigned short*)carve((size_t)M * 128 * 2);
    unsigned short* hb  = (unsigned short*)carve((size_t)M * 256 * 2);
    unsigned short* yb  = (unsigned short*)carve((size_t)MB * 4 * 16384 * 2);  // tiled, stage3-max
    unsigned short* v1  = (unsigned short*)carve((size_t)M * 128 * 2);
    unsigned short* v2  = (unsigned short*)carve((size_t)M * 256 * 2);
    unsigned short* xv1 = (unsigned short*)carve((size_t)M * 128 * 2);
    unsigned short* xv2 = (unsigned short*)carve((size_t)M * 256 * 2);
    unsigned short* WT1g = (unsigned short*)carve(128 * 128 * 2);
    unsigned short* WT1e = (unsigned short*)carve(128 * 128 * 2);
    unsigned short* WT2g = (unsigned short*)carve(256 * 128 * 2);
    unsigned short* WT2e = (unsigned short*)carve(256 * 128 * 2);
    unsigned short* WT3g = (unsigned short*)carve(512 * 256 * 2);
    unsigned short* WT3e = (unsigned short*)carve(512 * 256 * 2);
    float* stats = (float*)carve(3 * 1024 * 4);  // per stage: s1[512], s2[512]

    hipMemsetAsync(deg, 0, (size_t)M * 4, stream);
    hipMemsetAsync(stats, 0, 3 * 1024 * 4, stream);

    // input conversion + weight prep (single kernel)
    {
        int total = M * 128 + 2 * (16384 + 32768 + 131072);
        prep_all_kernel<<<(total + 255) / 256, 256, 0, stream>>>(
            v, vbf, W1, We1, WT1g, WT1e, W2, We2, WT2g, WT2e, W3, We3, WT3g, WT3e, M);
    }

    // CSR build (coalesced 3-kernel scan)
    const int NB = (M + 1023) / 1024;
    count_deg_kernel<<<(E + 255) / 256, 256, 0, stream>>>(dst, E, deg);
    scan_reduce_kernel<<<NB, 256, 0, stream>>>(deg, M, bsum);
    scan_bsum_kernel<<<1, 1024, 0, stream>>>(bsum, NB, boff, off, M);
    scan_apply_kernel<<<NB, 256, 0, stream>>>(deg, M, boff, off, cur);
    fill_kernel<<<(E + 255) / 256, 256, 0, stream>>>(src, dst, E, cur, srcs);

    float* st;
    const ushort4v* yb4 = (const ushort4v*)yb;

    // ---------------- stage 1 (86(->128) -> 128) ----------------
    st = stats + 0 * 1024;
    gather_h_kernel<1><<<(M + 3) / 4, 256, 0, stream>>>(vbf, off, srcs, eps1, hb, M);
    mfma_gemm<128, 128, 0><<<dim3(1, MB), 256, 0, stream>>>(
        hb, WT1g, b1, nullptr, st, st + 512, nullptr, nullptr, yb, nullptr, M);
    mfma_gemm<128, 128, 1><<<dim3(1, MB), 256, 0, stream>>>(
        vbf, WT1e, be1, yb4, st, st + 512, g1, bt1, xv1, v1, M);

    // ---------------- stage 2 (128 -> 256) ----------------
    st = stats + 1 * 1024;
    gather_h_kernel<1><<<(M + 3) / 4, 256, 0, stream>>>(xv1, off, srcs, eps2, hb, M);
    mfma_gemm<128, 256, 0><<<dim3(2, MB), 256, 0, stream>>>(
        hb, WT2g, b2, nullptr, st, st + 512, nullptr, nullptr, yb, nullptr, M);
    mfma_gemm<128, 256, 1><<<dim3(2, MB), 256, 0, stream>>>(
        v1, WT2e, be2, yb4, st, st + 512, g2, bt2, xv2, v2, M);

    // ---------------- stage 3 (256 -> 512) ----------------
    st = stats + 2 * 1024;
    gather_h_kernel<2><<<(2 * M + 3) / 4, 256, 0, stream>>>(xv2, off, srcs, eps3, hb, M);
    mfma_gemm<256, 512, 0><<<dim3(4, MB), 256, 0, stream>>>(
        hb, WT3g, b3, nullptr, st, st + 512, nullptr, nullptr, yb, nullptr, M);
    mfma_gemm<256, 512, 2><<<dim3(4, MB), 256, 0, stream>>>(
        v2, WT3e, be3, yb4, st, st + 512, g3, bt3, (float*)d_out, nullptr, M);
}